// Round 1
// baseline (1920.767 us; speedup 1.0000x reference)
//
#include <hip/hip_runtime.h>
#include <math.h>

#define NB 4
#define CIN 64
#define CO 64
#define CM 32
#define H0 48
#define W0 48
#define HH 96
#define WW 96
#define LTOK (HH*WW)     // 9216 tokens per image
#define NH 4
#define NBUCK 64
#define CHUNK 144
#define NCHUNK 64        // LTOK / CHUNK
#define TOT (NH*LTOK)    // 36864
#define SB 512
#define NSB (TOT/SB)     // 72

// ---------------- bicubic upsample (jax.image.resize, cubic a=-0.5, half-pixel) ----------------
__device__ __forceinline__ void cubic_taps(int o, int insz, int* p, float* w) {
  int j = o >> 1;
  const float B0=-0.0234375f, B1=0.2265625f, B2=0.8671875f, B3=-0.0703125f;
  if ((o & 1) == 0) { p[0]=j-2;p[1]=j-1;p[2]=j;  p[3]=j+1; w[0]=B0;w[1]=B1;w[2]=B2;w[3]=B3; }
  else              { p[0]=j-1;p[1]=j;  p[2]=j+1;p[3]=j+2; w[0]=B3;w[1]=B2;w[2]=B1;w[3]=B0; }
  float s = 0.f;
  #pragma unroll
  for (int a=0;a<4;a++){ if (p[a] < 0 || p[a] >= insz) p[a] = -1; else s += w[a]; }
  float inv = 1.f / s;
  #pragma unroll
  for (int a=0;a<4;a++) w[a] *= inv;
}

__global__ void k_upsample(const float* __restrict__ x, float* __restrict__ up) {
  int i = blockIdx.x*blockDim.x + threadIdx.x;
  if (i >= NB*CIN*HH*WW) return;
  int ox = i % WW; int t = i / WW;
  int oy = t % HH; t /= HH;
  int c = t % CIN; int n = t / CIN;
  int px[4]; float wx[4]; cubic_taps(ox, W0, px, wx);
  int py[4]; float wy[4]; cubic_taps(oy, H0, py, wy);
  const float* src = x + ((size_t)(n*CIN + c))*H0*W0;
  float acc = 0.f;
  #pragma unroll
  for (int a=0;a<4;a++) {
    if (py[a] < 0) continue;
    const float* r = src + py[a]*W0;
    float ra = 0.f;
    #pragma unroll
    for (int b=0;b<4;b++) if (px[b] >= 0) ra = fmaf(wx[b], r[px[b]], ra);
    acc = fmaf(wy[a], ra, acc);
  }
  up[i] = acc;
}

// ---------------- direct 3x3 conv, pad 1. block = 96 threads = one output row ----------------
__global__ void k_conv3x3(const float* __restrict__ in, const float* __restrict__ w,
                          const float* __restrict__ bias, float* __restrict__ out,
                          int couts, int relu, int tr) {
  int gid = blockIdx.x;
  int oy = gid % HH; int t = gid / HH;
  int co = t % couts; int n = t / couts;
  int ox = threadIdx.x;                     // 0..95
  __shared__ float row[3][WW+2];
  const float* inb = in + (size_t)n*CIN*HH*WW;
  const float* wb  = w  + (size_t)co*CIN*9;
  float acc = bias[co];
  for (int ci = 0; ci < CIN; ci++) {
    for (int e = threadIdx.x; e < 3*(WW+2); e += blockDim.x) {
      int r = e / (WW+2), k = e % (WW+2);
      int iy = oy + r - 1, ix = k - 1;
      float v = 0.f;
      if (iy >= 0 && iy < HH && ix >= 0 && ix < WW) v = inb[((size_t)ci*HH + iy)*WW + ix];
      row[r][k] = v;
    }
    __syncthreads();
    const float* wc = wb + ci*9;
    #pragma unroll
    for (int r = 0; r < 3; r++)
      acc = fmaf(wc[r*3+2], row[r][ox+2], fmaf(wc[r*3+1], row[r][ox+1], fmaf(wc[r*3+0], row[r][ox], acc)));
    __syncthreads();
  }
  if (relu) acc = fmaxf(acc, 0.f);
  if (tr) out[((size_t)n*LTOK + oy*WW + ox)*couts + co] = acc;   // token-major [n][t][couts]
  else    out[((size_t)(n*couts + co)*HH + oy)*WW + ox] = acc;   // NCHW
}

// ---------------- 1x1 conv (conv_assembly) -> token-major [n][t][64] ----------------
__global__ void k_conv1x1(const float* __restrict__ in, const float* __restrict__ w,
                          const float* __restrict__ bias, float* __restrict__ out) {
  int i = blockIdx.x*blockDim.x + threadIdx.x;   // co fastest
  if (i >= NB*LTOK*CO) return;
  int co = i % CO; int t = (i / CO) % LTOK; int n = i / (CO*LTOK);
  const float* inb = in + (size_t)n*CIN*LTOK + t;
  float acc = bias[co];
  #pragma unroll 8
  for (int ci = 0; ci < CIN; ci++) acc = fmaf(w[co*CIN + ci], inb[(size_t)ci*LTOK], acc);
  out[i] = acc;
}

// ---------------- LSH hash: codes + per-block histogram (block-uniform h since 9216=18*512) --
__global__ void k_hash(const float* __restrict__ xe, const float* __restrict__ rot,
                       int* __restrict__ codes, int* __restrict__ hist) {
  int b  = blockIdx.x;           // 0..NB*NSB-1
  int n  = b / NSB;
  int bb = b % NSB;
  int j  = bb*SB + threadIdx.x;  // 0..TOT-1
  int h  = j / LTOK;             // uniform within block
  int t  = j % LTOK;
  __shared__ float rl[CM][NBUCK/2];
  __shared__ int lh[256];
  for (int e = threadIdx.x; e < 256; e += SB) lh[e] = 0;
  for (int e = threadIdx.x; e < CM*(NBUCK/2); e += SB) {
    int f = e / 32, i = e % 32;
    rl[f][i] = rot[(f*NH + h)*32 + i];
  }
  __syncthreads();
  float q[CM];
  const float* xr = xe + ((size_t)n*LTOK + t)*CM;
  #pragma unroll
  for (int f = 0; f < CM; f++) q[f] = xr[f];
  float bp = -INFINITY, bn = -INFINITY; int ip = 0, inn = 0;
  for (int i = 0; i < 32; i++) {
    float acc = 0.f;
    #pragma unroll
    for (int f = 0; f < CM; f++) acc = fmaf(q[f], rl[f][i], acc);
    if (acc  > bp) { bp = acc;  ip  = i; }
    if (-acc > bn) { bn = -acc; inn = i; }
  }
  int code = (bp >= bn) ? ip : (32 + inn);   // first-occurrence tie-break: positives first
  code += h * NBUCK;
  codes[n*TOT + j] = code;
  atomicAdd(&lh[code], 1);
  __syncthreads();
  for (int e = threadIdx.x; e < 256; e += SB) hist[((size_t)(n*NSB + bb))*256 + e] = lh[e];
}

// ---------------- stable counting sort: code totals scan + per-block starts ----------------
__global__ void k_offsets(const int* __restrict__ hist, int* __restrict__ bstart) {
  int n = blockIdx.x; int c = threadIdx.x;    // 256 threads
  int tot = 0;
  for (int b = 0; b < NSB; b++) tot += hist[((size_t)(n*NSB + b))*256 + c];
  __shared__ int sc[256];
  sc[c] = tot;
  __syncthreads();
  for (int d = 1; d < 256; d <<= 1) {
    int u = (c >= d) ? sc[c-d] : 0;
    __syncthreads();
    sc[c] += u;
    __syncthreads();
  }
  int run = sc[c] - tot;   // exclusive prefix over codes
  for (int b = 0; b < NSB; b++) {
    bstart[((size_t)(n*NSB + b))*256 + c] = run;
    run += hist[((size_t)(n*NSB + b))*256 + c];
  }
}

__global__ void k_scatter(const int* __restrict__ codes, const int* __restrict__ bstart,
                          int* __restrict__ sidx) {
  int b = blockIdx.x; int n = b / NSB; int bb = b % NSB;
  int j = bb*SB + threadIdx.x;
  int code = codes[n*TOT + j];
  __shared__ unsigned char lc[SB];
  lc[threadIdx.x] = (unsigned char)code;
  __syncthreads();
  int rank = 0;
  unsigned char my = (unsigned char)code;
  for (int e = 0; e < threadIdx.x; e++) rank += (lc[e] == my) ? 1 : 0;
  int pos = bstart[((size_t)(n*NSB + bb))*256 + code] + rank;
  sidx[n*TOT + pos] = j;    // idx[s] = original flat index (h*L + t)
}

// ---------------- chunked attention with online softmax; scatter to unsorted order ----------
__global__ __launch_bounds__(192) void k_attn(const float* __restrict__ xe, const float* __restrict__ ye,
                       const int* __restrict__ sidx, float* __restrict__ ret,
                       float* __restrict__ bsc) {
  int blk = blockIdx.x;               // 1024 = NB*NH*NCHUNK
  int k = blk % NCHUNK;
  int h = (blk / NCHUNK) % NH;
  int n = blk / (NCHUNK*NH);
  const int base = n*TOT + h*LTOK;    // into sidx
  __shared__ float Kt[CHUNK][CM+1];
  __shared__ float Vt[CHUNK][CO];
  __shared__ float rn[CHUNK];
  int tid = threadIdx.x;

  float q[CM];
  int myti = 0;
  if (tid < CHUNK) {
    myti = sidx[base + k*CHUNK + tid];          // in [0, TOT)
    const float* xr = xe + ((size_t)n*LTOK + (myti % LTOK))*CM;
    #pragma unroll
    for (int f = 0; f < CM; f++) q[f] = xr[f];
  }
  float m = -INFINITY, ssum = 0.f;
  float acc[CO];
  #pragma unroll
  for (int e = 0; e < CO; e++) acc[e] = 0.f;

  for (int tt = 0; tt < 3; tt++) {
    int kk = (tt == 0) ? k : ((tt == 1) ? (k + NCHUNK - 1) % NCHUNK : (k + 1) % NCHUNK);
    __syncthreads();   // previous tile fully consumed
    for (int e = tid; e < CHUNK*CM; e += 192) {
      int r = e >> 5, f = e & 31;
      int tj = sidx[base + kk*CHUNK + r] % LTOK;
      Kt[r][f] = xe[((size_t)n*LTOK + tj)*CM + f];
    }
    for (int e = tid; e < CHUNK*CO; e += 192) {
      int r = e >> 6, f = e & 63;
      int tj = sidx[base + kk*CHUNK + r] % LTOK;
      Vt[r][f] = ye[((size_t)n*LTOK + tj)*CO + f];
    }
    __syncthreads();
    if (tid < CHUNK) {
      float ss = 0.f;
      #pragma unroll
      for (int f = 0; f < CM; f++) { float v = Kt[tid][f]; ss = fmaf(v, v, ss); }
      rn[tid] = 1.f / fmaxf(sqrtf(ss), 5e-5f);
    }
    __syncthreads();
    if (tid < CHUNK) {
      for (int j = 0; j < CHUNK; j++) {
        float s = 0.f;
        #pragma unroll
        for (int f = 0; f < CM; f++) s = fmaf(q[f], Kt[j][f], s);
        s *= rn[j];
        float p;
        if (s > m) {
          float scl = __expf(m - s);
          ssum *= scl;
          #pragma unroll
          for (int e = 0; e < CO; e++) acc[e] *= scl;
          m = s; p = 1.f;
        } else {
          p = __expf(s - m);
        }
        ssum += p;
        #pragma unroll
        for (int e = 0; e < CO; e++) acc[e] = fmaf(p, Vt[j][e], acc[e]);
      }
    }
  }
  if (tid < CHUNK) {
    float inv = 1.f / ssum;
    float* rp = ret + ((size_t)n*TOT + myti)*CO;   // unsorted [n][h*L+t][64]
    #pragma unroll
    for (int e = 0; e < CO; e++) rp[e] = acc[e] * inv;
    bsc[(size_t)n*TOT + myti] = m + logf(ssum);
  }
}

// ---------------- combine 4 hash rounds (softmax over bscore) + residual, NCHW out ----------
__global__ void k_combine(const float* __restrict__ ret, const float* __restrict__ bsc,
                          const float* __restrict__ c2, float* __restrict__ out) {
  int blk = blockIdx.x;                 // NB * (LTOK/16)
  int n  = blk / (LTOK/16);
  int t0 = (blk % (LTOK/16)) * 16;
  __shared__ float rl[NH][16][CO+1];
  __shared__ float pw[NH][16];
  int tid = threadIdx.x;
  for (int h = 0; h < NH; h++)
    for (int e = tid; e < 16*CO; e += 256) {
      int tl = e >> 6, f = e & 63;
      rl[h][tl][f] = ret[((size_t)n*TOT + h*LTOK + t0 + tl)*CO + f];
    }
  if (tid < 16) {
    float b0[NH]; float mm = -INFINITY;
    #pragma unroll
    for (int h = 0; h < NH; h++) { b0[h] = bsc[(size_t)n*TOT + h*LTOK + t0 + tid]; mm = fmaxf(mm, b0[h]); }
    float s = 0.f;
    #pragma unroll
    for (int h = 0; h < NH; h++) { b0[h] = __expf(b0[h] - mm); s += b0[h]; }
    float inv = 1.f / s;
    #pragma unroll
    for (int h = 0; h < NH; h++) pw[h][tid] = b0[h] * inv;
  }
  __syncthreads();
  int tl = tid & 15;
  int cog = tid >> 4;     // 0..15
  #pragma unroll
  for (int cc = 0; cc < 4; cc++) {
    int co = cog + 16*cc;
    size_t oi = ((size_t)(n*CO + co))*LTOK + t0 + tl;
    float a = c2[oi];
    #pragma unroll
    for (int h = 0; h < NH; h++) a = fmaf(pw[h][tl], rl[h][tl][co], a);
    out[oi] = a;
  }
}

extern "C" void kernel_launch(void* const* d_in, const int* in_sizes, int n_in,
                              void* d_out, int out_size, void* d_ws, size_t ws_size,
                              hipStream_t stream) {
  const float* x   = (const float*)d_in[0];
  const float* w1  = (const float*)d_in[1];
  const float* b1  = (const float*)d_in[2];
  const float* w2  = (const float*)d_in[3];
  const float* b2  = (const float*)d_in[4];
  const float* wm  = (const float*)d_in[5];
  const float* bm  = (const float*)d_in[6];
  const float* wa  = (const float*)d_in[7];
  const float* ba  = (const float*)d_in[8];
  const float* rot = (const float*)d_in[9];
  float* out = (float*)d_out;

  float* ws  = (float*)d_ws;
  float* up  = ws;                    // 2359296
  float* c1  = up  + 2359296;         // 2359296
  float* c2  = c1  + 2359296;         // 2359296
  float* xep = c2  + 2359296;         // 1179648  [n][t][32]
  float* yep = xep + 1179648;         // 2359296  [n][t][64]
  float* bsc = yep + 2359296;         // 147456   [n][h*L+t]
  float* ret = bsc + 147456;          // 9437184  [n][h*L+t][64]
  int* codes  = (int*)(ret + 9437184);// 147456
  int* sidx   = codes + 147456;       // 147456
  int* hist   = sidx + 147456;        // 73728
  int* bstart = hist + 73728;         // 73728
  (void)in_sizes; (void)n_in; (void)out_size; (void)ws_size;

  k_upsample<<<dim3((NB*CIN*HH*WW + 255)/256), dim3(256), 0, stream>>>(x, up);
  k_conv3x3<<<dim3(NB*CO*HH), dim3(96), 0, stream>>>(up, w1, b1, c1, CO, 1, 0);
  k_conv3x3<<<dim3(NB*CO*HH), dim3(96), 0, stream>>>(c1, w2, b2, c2, CO, 1, 0);
  k_conv3x3<<<dim3(NB*CM*HH), dim3(96), 0, stream>>>(c2, wm, bm, xep, CM, 0, 1);
  k_conv1x1<<<dim3((NB*LTOK*CO + 255)/256), dim3(256), 0, stream>>>(c2, wa, ba, yep);
  k_hash<<<dim3(NB*NSB), dim3(SB), 0, stream>>>(xep, rot, codes, hist);
  k_offsets<<<dim3(NB), dim3(256), 0, stream>>>(hist, bstart);
  k_scatter<<<dim3(NB*NSB), dim3(SB), 0, stream>>>(codes, bstart, sidx);
  k_attn<<<dim3(NB*NH*NCHUNK), dim3(192), 0, stream>>>(xep, yep, sidx, ret, bsc);
  k_combine<<<dim3(NB*(LTOK/16)), dim3(256), 0, stream>>>(ret, bsc, c2, out);
}

// Round 2
// 1273.419 us; speedup vs baseline: 1.5084x; 1.5084x over previous
//
#include <hip/hip_runtime.h>
#include <math.h>

#define NB 4
#define CIN 64
#define CO 64
#define CM 32
#define H0 48
#define W0 48
#define HH 96
#define WW 96
#define LTOK (HH*WW)     // 9216 tokens per image
#define NH 4
#define NBUCK 64
#define CHUNK 144
#define NCHUNK 64        // LTOK / CHUNK
#define TOT (NH*LTOK)    // 36864
#define SB 512
#define NSB (TOT/SB)     // 72

// ---------------- bicubic upsample (jax.image.resize, cubic a=-0.5, half-pixel) ----------------
__device__ __forceinline__ void cubic_taps(int o, int insz, int* p, float* w) {
  int j = o >> 1;
  const float B0=-0.0234375f, B1=0.2265625f, B2=0.8671875f, B3=-0.0703125f;
  if ((o & 1) == 0) { p[0]=j-2;p[1]=j-1;p[2]=j;  p[3]=j+1; w[0]=B0;w[1]=B1;w[2]=B2;w[3]=B3; }
  else              { p[0]=j-1;p[1]=j;  p[2]=j+1;p[3]=j+2; w[0]=B3;w[1]=B2;w[2]=B1;w[3]=B0; }
  float s = 0.f;
  #pragma unroll
  for (int a=0;a<4;a++){ if (p[a] < 0 || p[a] >= insz) p[a] = -1; else s += w[a]; }
  float inv = 1.f / s;
  #pragma unroll
  for (int a=0;a<4;a++) w[a] *= inv;
}

__global__ void k_upsample(const float* __restrict__ x, float* __restrict__ up) {
  int i = blockIdx.x*blockDim.x + threadIdx.x;
  if (i >= NB*CIN*HH*WW) return;
  int ox = i % WW; int t = i / WW;
  int oy = t % HH; t /= HH;
  int c = t % CIN; int n = t / CIN;
  int px[4]; float wx[4]; cubic_taps(ox, W0, px, wx);
  int py[4]; float wy[4]; cubic_taps(oy, H0, py, wy);
  const float* src = x + ((size_t)(n*CIN + c))*H0*W0;
  float acc = 0.f;
  #pragma unroll
  for (int a=0;a<4;a++) {
    if (py[a] < 0) continue;
    const float* r = src + py[a]*W0;
    float ra = 0.f;
    #pragma unroll
    for (int b=0;b<4;b++) if (px[b] >= 0) ra = fmaf(wx[b], r[px[b]], ra);
    acc = fmaf(wy[a], ra, acc);
  }
  up[i] = acc;
}

// ---------------- 3x3 conv, pad 1. block = 256 thr = 32co x 8 xgroups x 12px register tile ----
__global__ __launch_bounds__(256) void k_conv3(const float* __restrict__ in, const float* __restrict__ w,
                          const float* __restrict__ bias, float* __restrict__ out,
                          int couts, int relu, int tr, int cosplit) {
  int gid = blockIdx.x;
  int ch = gid % cosplit;
  int oy = (gid / cosplit) % HH;
  int n  = gid / (cosplit*HH);
  int tid = threadIdx.x;
  int lco = tid & 31;
  int co  = ch*32 + lco;
  int xg  = tid >> 5;            // 0..7
  int xb  = xg*12;
  __shared__ float rows[3][WW+2];
  __shared__ float wl[288];
  float acc[12];
  float bv = bias[co];
  #pragma unroll
  for (int i=0;i<12;i++) acc[i]=bv;
  const float* inb = in + (size_t)n*CIN*HH*WW;
  for (int ci=0; ci<CIN; ci++) {
    __syncthreads();
    for (int e=tid; e<3*(WW+2); e+=256) {
      int r=e/(WW+2), kx=e%(WW+2);
      int iy=oy+r-1, ix=kx-1;
      float v=0.f;
      if (iy>=0 && iy<HH && ix>=0 && ix<WW) v=inb[((size_t)ci*HH+iy)*WW+ix];
      rows[r][kx]=v;
    }
    for (int e=tid; e<288; e+=256) {
      int c=e/9, kk=e%9;
      wl[e] = w[((size_t)(ch*32+c)*CIN + ci)*9 + kk];
    }
    __syncthreads();
    float wr[9];
    #pragma unroll
    for (int u=0;u<9;u++) wr[u]=wl[lco*9+u];
    #pragma unroll
    for (int r=0;r<3;r++) {
      #pragma unroll
      for (int i=0;i<12;i++) {
        acc[i]=fmaf(wr[r*3+0], rows[r][xb+i],   acc[i]);
        acc[i]=fmaf(wr[r*3+1], rows[r][xb+i+1], acc[i]);
        acc[i]=fmaf(wr[r*3+2], rows[r][xb+i+2], acc[i]);
      }
    }
  }
  if (relu) {
    #pragma unroll
    for (int i=0;i<12;i++) acc[i]=fmaxf(acc[i],0.f);
  }
  if (tr) {  // token-major [n][t][couts]
    #pragma unroll
    for (int i=0;i<12;i++)
      out[((size_t)n*LTOK + oy*WW + xb+i)*couts + co] = acc[i];
  } else {   // NCHW
    float4* op = (float4*)(out + ((size_t)(n*couts+co)*HH + oy)*WW + xb);
    op[0]=make_float4(acc[0],acc[1],acc[2],acc[3]);
    op[1]=make_float4(acc[4],acc[5],acc[6],acc[7]);
    op[2]=make_float4(acc[8],acc[9],acc[10],acc[11]);
  }
}

// ---------------- 1x1 conv as LDS-tiled GEMM: 64co x 128tok x 64ci per block ----------------
__global__ __launch_bounds__(256) void k_conv1x1(const float* __restrict__ in, const float* __restrict__ w,
                          const float* __restrict__ bias, float* __restrict__ out) {
  int blk = blockIdx.x;           // NB * 72
  int n  = blk / (LTOK/128);
  int t0 = (blk % (LTOK/128)) * 128;
  int tid = threadIdx.x;
  __shared__ float Wl[64*64];     // [ci][co]
  __shared__ float Xl[64][128];
  for (int e=tid; e<4096; e+=256) {
    int ci=e>>6, co=e&63;
    Wl[e] = w[co*CIN + ci];       // transposed store; one-time
  }
  for (int e=tid; e<64*128; e+=256) {
    int ci=e>>7, t=e&127;
    Xl[ci][t] = in[(size_t)n*CIN*LTOK + (size_t)ci*LTOK + t0 + t];
  }
  __syncthreads();
  int co = tid & 63, tg = tid >> 6;   // tg uniform per wave
  float acc[32];
  float bv = bias[co];
  #pragma unroll
  for (int i=0;i<32;i++) acc[i]=bv;
  for (int ci=0;ci<64;ci++){
    float wv = Wl[ci*64+co];
    const float4* xr = (const float4*)&Xl[ci][tg*32];
    #pragma unroll
    for (int r=0;r<8;r++){
      float4 xv = xr[r];
      acc[4*r+0]=fmaf(wv,xv.x,acc[4*r+0]);
      acc[4*r+1]=fmaf(wv,xv.y,acc[4*r+1]);
      acc[4*r+2]=fmaf(wv,xv.z,acc[4*r+2]);
      acc[4*r+3]=fmaf(wv,xv.w,acc[4*r+3]);
    }
  }
  float* ob = out + ((size_t)n*LTOK + t0 + tg*32)*CO + co;
  #pragma unroll
  for (int i=0;i<32;i++) ob[(size_t)i*CO] = acc[i];
}

// ---------------- LSH hash: codes + per-block histogram (block-uniform h since 9216=18*512) --
__global__ void k_hash(const float* __restrict__ xe, const float* __restrict__ rot,
                       int* __restrict__ codes, int* __restrict__ hist) {
  int b  = blockIdx.x;           // 0..NB*NSB-1
  int n  = b / NSB;
  int bb = b % NSB;
  int j  = bb*SB + threadIdx.x;  // 0..TOT-1
  int h  = j / LTOK;             // uniform within block
  int t  = j % LTOK;
  __shared__ float rl[CM][NBUCK/2];
  __shared__ int lh[256];
  for (int e = threadIdx.x; e < 256; e += SB) lh[e] = 0;
  for (int e = threadIdx.x; e < CM*(NBUCK/2); e += SB) {
    int f = e / 32, i = e % 32;
    rl[f][i] = rot[(f*NH + h)*32 + i];
  }
  __syncthreads();
  float q[CM];
  const float4* xr4 = (const float4*)(xe + ((size_t)n*LTOK + t)*CM);
  #pragma unroll
  for (int r = 0; r < 8; r++) {
    float4 v = xr4[r];
    q[4*r+0]=v.x; q[4*r+1]=v.y; q[4*r+2]=v.z; q[4*r+3]=v.w;
  }
  float bp = -INFINITY, bn = -INFINITY; int ip = 0, inn = 0;
  for (int i = 0; i < 32; i++) {
    float acc = 0.f;
    #pragma unroll
    for (int f = 0; f < CM; f++) acc = fmaf(q[f], rl[f][i], acc);
    if (acc  > bp) { bp = acc;  ip  = i; }
    if (-acc > bn) { bn = -acc; inn = i; }
  }
  int code = (bp >= bn) ? ip : (32 + inn);   // first-occurrence tie-break: positives first
  code += h * NBUCK;
  codes[n*TOT + j] = code;
  atomicAdd(&lh[code], 1);
  __syncthreads();
  for (int e = threadIdx.x; e < 256; e += SB) hist[((size_t)(n*NSB + bb))*256 + e] = lh[e];
}

// ---------------- stable counting sort: code totals scan + per-block starts ----------------
__global__ void k_offsets(const int* __restrict__ hist, int* __restrict__ bstart) {
  int n = blockIdx.x; int c = threadIdx.x;    // 256 threads
  int tot = 0;
  for (int b = 0; b < NSB; b++) tot += hist[((size_t)(n*NSB + b))*256 + c];
  __shared__ int sc[256];
  sc[c] = tot;
  __syncthreads();
  for (int d = 1; d < 256; d <<= 1) {
    int u = (c >= d) ? sc[c-d] : 0;
    __syncthreads();
    sc[c] += u;
    __syncthreads();
  }
  int run = sc[c] - tot;   // exclusive prefix over codes
  for (int b = 0; b < NSB; b++) {
    bstart[((size_t)(n*NSB + b))*256 + c] = run;
    run += hist[((size_t)(n*NSB + b))*256 + c];
  }
}

__global__ void k_scatter(const int* __restrict__ codes, const int* __restrict__ bstart,
                          int* __restrict__ sidx) {
  int b = blockIdx.x; int n = b / NSB; int bb = b % NSB;
  int j = bb*SB + threadIdx.x;
  int code = codes[n*TOT + j];
  __shared__ unsigned char lc[SB];
  lc[threadIdx.x] = (unsigned char)code;
  __syncthreads();
  int rank = 0;
  unsigned char my = (unsigned char)code;
  for (int e = 0; e < threadIdx.x; e++) rank += (lc[e] == my) ? 1 : 0;
  int pos = bstart[((size_t)(n*NSB + bb))*256 + code] + rank;
  sidx[n*TOT + pos] = j;    // idx[s] = original flat index (h*L + t)
}

// ---------------- chunked attention: 2 queries/thread, fixed m = ||q|| (self-match is max) ---
__global__ __launch_bounds__(192,1) void k_attn(const float* __restrict__ xe, const float* __restrict__ ye,
                       const int* __restrict__ sidx, float* __restrict__ ret,
                       float* __restrict__ bsc) {
  int blk = blockIdx.x;               // 1024 = NB*NH*NCHUNK
  int k = blk % NCHUNK;
  int h = (blk / NCHUNK) % NH;
  int n = blk / (NCHUNK*NH);
  const int base = n*TOT + h*LTOK;    // into sidx
  __shared__ float Kt[CHUNK][36];     // normalized keys, padded to 16B multiple
  __shared__ float Vt[CHUNK][68];     // padded to 16B multiple
  __shared__ float rns[CHUNK];
  __shared__ int   sj[CHUNK];
  int tid = threadIdx.x;

  float q0[32], q1[32], acc0[64], acc1[64];
  float m0=0.f, m1=0.f, ss0=0.f, ss1=0.f;
  int mt0=0, mt1=0;
  if (tid < 72) {
    mt0 = sidx[base + k*CHUNK + tid];
    mt1 = sidx[base + k*CHUNK + tid + 72];
    const float4* a = (const float4*)(xe + ((size_t)n*LTOK + (mt0 % LTOK))*CM);
    const float4* b = (const float4*)(xe + ((size_t)n*LTOK + (mt1 % LTOK))*CM);
    float n0=0.f, n1=0.f;
    #pragma unroll
    for (int r=0;r<8;r++){
      float4 v=a[r]; q0[4*r]=v.x; q0[4*r+1]=v.y; q0[4*r+2]=v.z; q0[4*r+3]=v.w;
      float4 u=b[r]; q1[4*r]=u.x; q1[4*r+1]=u.y; q1[4*r+2]=u.z; q1[4*r+3]=u.w;
    }
    #pragma unroll
    for (int f=0;f<32;f++){ n0=fmaf(q0[f],q0[f],n0); n1=fmaf(q1[f],q1[f],n1); }
    m0 = sqrtf(n0); m1 = sqrtf(n1);   // exact max score: self key is in chunk, cos<=1
    #pragma unroll
    for (int e=0;e<64;e++){ acc0[e]=0.f; acc1[e]=0.f; }
  }

  for (int tt = 0; tt < 3; tt++) {
    int kk = (tt == 0) ? k : ((tt == 1) ? (k + NCHUNK - 1) % NCHUNK : (k + 1) % NCHUNK);
    __syncthreads();   // previous tile fully consumed
    if (tid < CHUNK) sj[tid] = sidx[base + kk*CHUNK + tid] % LTOK;
    __syncthreads();
    for (int e = tid; e < CHUNK*CM; e += 192) {
      int r = e >> 5, f = e & 31;
      Kt[r][f] = xe[((size_t)n*LTOK + sj[r])*CM + f];
    }
    for (int e = tid; e < CHUNK*CO; e += 192) {
      int r = e >> 6, f = e & 63;
      Vt[r][f] = ye[((size_t)n*LTOK + sj[r])*CO + f];
    }
    __syncthreads();
    if (tid < CHUNK) {
      float ssq = 0.f;
      const float4* kr = (const float4*)Kt[tid];
      #pragma unroll
      for (int r=0;r<8;r++){ float4 v=kr[r]; ssq=fmaf(v.x,v.x,ssq); ssq=fmaf(v.y,v.y,ssq); ssq=fmaf(v.z,v.z,ssq); ssq=fmaf(v.w,v.w,ssq); }
      rns[tid] = 1.f / fmaxf(sqrtf(ssq), 5e-5f);
    }
    __syncthreads();
    for (int e = tid; e < CHUNK*CM; e += 192) {
      int r = e >> 5, f = e & 31;
      Kt[r][f] *= rns[r];
    }
    __syncthreads();
    if (tid < 72) {
      for (int j = 0; j < CHUNK; j++) {
        const float4* kr = (const float4*)Kt[j];
        float s0=0.f, s1=0.f;
        #pragma unroll
        for (int r=0;r<8;r++){
          float4 kv = kr[r];
          s0=fmaf(q0[4*r],kv.x,s0); s0=fmaf(q0[4*r+1],kv.y,s0); s0=fmaf(q0[4*r+2],kv.z,s0); s0=fmaf(q0[4*r+3],kv.w,s0);
          s1=fmaf(q1[4*r],kv.x,s1); s1=fmaf(q1[4*r+1],kv.y,s1); s1=fmaf(q1[4*r+2],kv.z,s1); s1=fmaf(q1[4*r+3],kv.w,s1);
        }
        float p0 = __expf(s0 - m0);
        float p1 = __expf(s1 - m1);
        ss0 += p0; ss1 += p1;
        const float4* vr = (const float4*)Vt[j];
        #pragma unroll
        for (int r=0;r<16;r++){
          float4 vv = vr[r];
          acc0[4*r+0]=fmaf(p0,vv.x,acc0[4*r+0]); acc0[4*r+1]=fmaf(p0,vv.y,acc0[4*r+1]);
          acc0[4*r+2]=fmaf(p0,vv.z,acc0[4*r+2]); acc0[4*r+3]=fmaf(p0,vv.w,acc0[4*r+3]);
          acc1[4*r+0]=fmaf(p1,vv.x,acc1[4*r+0]); acc1[4*r+1]=fmaf(p1,vv.y,acc1[4*r+1]);
          acc1[4*r+2]=fmaf(p1,vv.z,acc1[4*r+2]); acc1[4*r+3]=fmaf(p1,vv.w,acc1[4*r+3]);
        }
      }
    }
  }
  if (tid < 72) {
    float inv0 = 1.f / ss0, inv1 = 1.f / ss1;
    float4* r0 = (float4*)(ret + ((size_t)n*TOT + mt0)*CO);
    float4* r1 = (float4*)(ret + ((size_t)n*TOT + mt1)*CO);
    #pragma unroll
    for (int r=0;r<16;r++){
      r0[r] = make_float4(acc0[4*r]*inv0, acc0[4*r+1]*inv0, acc0[4*r+2]*inv0, acc0[4*r+3]*inv0);
      r1[r] = make_float4(acc1[4*r]*inv1, acc1[4*r+1]*inv1, acc1[4*r+2]*inv1, acc1[4*r+3]*inv1);
    }
    bsc[(size_t)n*TOT + mt0] = m0 + logf(ss0);
    bsc[(size_t)n*TOT + mt1] = m1 + logf(ss1);
  }
}

// ---------------- combine 4 hash rounds (softmax over bscore) + residual, NCHW out ----------
__global__ void k_combine(const float* __restrict__ ret, const float* __restrict__ bsc,
                          const float* __restrict__ c2, float* __restrict__ out) {
  int blk = blockIdx.x;                 // NB * (LTOK/16)
  int n  = blk / (LTOK/16);
  int t0 = (blk % (LTOK/16)) * 16;
  __shared__ float rl[NH][16][CO+1];
  __shared__ float pw[NH][16];
  int tid = threadIdx.x;
  for (int h = 0; h < NH; h++)
    for (int e = tid; e < 16*CO; e += 256) {
      int tl = e >> 6, f = e & 63;
      rl[h][tl][f] = ret[((size_t)n*TOT + h*LTOK + t0 + tl)*CO + f];
    }
  if (tid < 16) {
    float b0[NH]; float mm = -INFINITY;
    #pragma unroll
    for (int h = 0; h < NH; h++) { b0[h] = bsc[(size_t)n*TOT + h*LTOK + t0 + tid]; mm = fmaxf(mm, b0[h]); }
    float s = 0.f;
    #pragma unroll
    for (int h = 0; h < NH; h++) { b0[h] = __expf(b0[h] - mm); s += b0[h]; }
    float inv = 1.f / s;
    #pragma unroll
    for (int h = 0; h < NH; h++) pw[h][tid] = b0[h] * inv;
  }
  __syncthreads();
  int tl = tid & 15;
  int cog = tid >> 4;     // 0..15
  #pragma unroll
  for (int cc = 0; cc < 4; cc++) {
    int co = cog + 16*cc;
    size_t oi = ((size_t)(n*CO + co))*LTOK + t0 + tl;
    float a = c2[oi];
    #pragma unroll
    for (int h = 0; h < NH; h++) a = fmaf(pw[h][tl], rl[h][tl][co], a);
    out[oi] = a;
  }
}

extern "C" void kernel_launch(void* const* d_in, const int* in_sizes, int n_in,
                              void* d_out, int out_size, void* d_ws, size_t ws_size,
                              hipStream_t stream) {
  const float* x   = (const float*)d_in[0];
  const float* w1  = (const float*)d_in[1];
  const float* b1  = (const float*)d_in[2];
  const float* w2  = (const float*)d_in[3];
  const float* b2  = (const float*)d_in[4];
  const float* wm  = (const float*)d_in[5];
  const float* bm  = (const float*)d_in[6];
  const float* wa  = (const float*)d_in[7];
  const float* ba  = (const float*)d_in[8];
  const float* rot = (const float*)d_in[9];
  float* out = (float*)d_out;

  float* ws  = (float*)d_ws;
  float* up  = ws;                    // 2359296
  float* c1  = up  + 2359296;         // 2359296
  float* c2  = c1  + 2359296;         // 2359296
  float* xep = c2  + 2359296;         // 1179648  [n][t][32]
  float* yep = xep + 1179648;         // 2359296  [n][t][64]
  float* bsc = yep + 2359296;         // 147456   [n][h*L+t]
  float* ret = bsc + 147456;          // 9437184  [n][h*L+t][64]
  int* codes  = (int*)(ret + 9437184);// 147456
  int* sidx   = codes + 147456;       // 147456
  int* hist   = sidx + 147456;        // 73728
  int* bstart = hist + 73728;         // 73728
  (void)in_sizes; (void)n_in; (void)out_size; (void)ws_size;

  k_upsample<<<dim3((NB*CIN*HH*WW + 255)/256), dim3(256), 0, stream>>>(x, up);
  k_conv3<<<dim3(NB*HH*2), dim3(256), 0, stream>>>(up, w1, b1, c1, CO, 1, 0, 2);
  k_conv3<<<dim3(NB*HH*2), dim3(256), 0, stream>>>(c1, w2, b2, c2, CO, 1, 0, 2);
  k_conv3<<<dim3(NB*HH*1), dim3(256), 0, stream>>>(c2, wm, bm, xep, CM, 0, 1, 1);
  k_conv1x1<<<dim3(NB*(LTOK/128)), dim3(256), 0, stream>>>(c2, wa, ba, yep);
  k_hash<<<dim3(NB*NSB), dim3(SB), 0, stream>>>(xep, rot, codes, hist);
  k_offsets<<<dim3(NB), dim3(256), 0, stream>>>(hist, bstart);
  k_scatter<<<dim3(NB*NSB), dim3(SB), 0, stream>>>(codes, bstart, sidx);
  k_attn<<<dim3(NB*NH*NCHUNK), dim3(192), 0, stream>>>(xep, yep, sidx, ret, bsc);
  k_combine<<<dim3(NB*(LTOK/16)), dim3(256), 0, stream>>>(ret, bsc, c2, out);
}

// Round 3
// 554.378 us; speedup vs baseline: 3.4647x; 2.2970x over previous
//
#include <hip/hip_runtime.h>
#include <math.h>

#define NB 4
#define CIN 64
#define CO 64
#define CM 32
#define H0 48
#define W0 48
#define HH 96
#define WW 96
#define LTOK (HH*WW)     // 9216 tokens per image
#define NH 4
#define NBUCK 64
#define CHUNK 144
#define NCHUNK 64        // LTOK / CHUNK
#define TOT (NH*LTOK)    // 36864
#define SB 512
#define NSB (TOT/SB)     // 72

typedef __attribute__((ext_vector_type(8))) short short8;
typedef __attribute__((ext_vector_type(4))) float f32x4;

__device__ __forceinline__ short f2bf(float f) {
  union { float f; unsigned u; } v; v.f = f;
  unsigned r = v.u + 0x7fffu + ((v.u >> 16) & 1u);
  return (short)(r >> 16);
}

// ---------------- bicubic upsample (jax.image.resize, cubic a=-0.5, half-pixel) ----------------
__device__ __forceinline__ void cubic_taps(int o, int insz, int* p, float* w) {
  int j = o >> 1;
  const float B0=-0.0234375f, B1=0.2265625f, B2=0.8671875f, B3=-0.0703125f;
  if ((o & 1) == 0) { p[0]=j-2;p[1]=j-1;p[2]=j;  p[3]=j+1; w[0]=B0;w[1]=B1;w[2]=B2;w[3]=B3; }
  else              { p[0]=j-1;p[1]=j;  p[2]=j+1;p[3]=j+2; w[0]=B3;w[1]=B2;w[2]=B1;w[3]=B0; }
  float s = 0.f;
  #pragma unroll
  for (int a=0;a<4;a++){ if (p[a] < 0 || p[a] >= insz) p[a] = -1; else s += w[a]; }
  float inv = 1.f / s;
  #pragma unroll
  for (int a=0;a<4;a++) w[a] *= inv;
}

__global__ void k_upsample(const float* __restrict__ x, float* __restrict__ up) {
  int i = blockIdx.x*blockDim.x + threadIdx.x;
  if (i >= NB*CIN*HH*WW) return;
  int ox = i % WW; int t = i / WW;
  int oy = t % HH; t /= HH;
  int c = t % CIN; int n = t / CIN;
  int px[4]; float wx[4]; cubic_taps(ox, W0, px, wx);
  int py[4]; float wy[4]; cubic_taps(oy, H0, py, wy);
  const float* src = x + ((size_t)(n*CIN + c))*H0*W0;
  float acc = 0.f;
  #pragma unroll
  for (int a=0;a<4;a++) {
    if (py[a] < 0) continue;
    const float* r = src + py[a]*W0;
    float ra = 0.f;
    #pragma unroll
    for (int b=0;b<4;b++) if (px[b] >= 0) ra = fmaf(wx[b], r[px[b]], ra);
    acc = fmaf(wy[a], ra, acc);
  }
  up[i] = acc;
}

// ---------------- 3x3 conv, pad 1. block = 256 thr = 32co x 8 xgroups x 12px register tile ----
__global__ __launch_bounds__(256) void k_conv3(const float* __restrict__ in, const float* __restrict__ w,
                          const float* __restrict__ bias, float* __restrict__ out,
                          int couts, int relu, int tr, int cosplit) {
  int gid = blockIdx.x;
  int ch = gid % cosplit;
  int oy = (gid / cosplit) % HH;
  int n  = gid / (cosplit*HH);
  int tid = threadIdx.x;
  int lco = tid & 31;
  int co  = ch*32 + lco;
  int xg  = tid >> 5;            // 0..7
  int xb  = xg*12;
  __shared__ float rows[3][WW+2];
  __shared__ float wl[288];
  float acc[12];
  float bv = bias[co];
  #pragma unroll
  for (int i=0;i<12;i++) acc[i]=bv;
  const float* inb = in + (size_t)n*CIN*HH*WW;
  for (int ci=0; ci<CIN; ci++) {
    __syncthreads();
    for (int e=tid; e<3*(WW+2); e+=256) {
      int r=e/(WW+2), kx=e%(WW+2);
      int iy=oy+r-1, ix=kx-1;
      float v=0.f;
      if (iy>=0 && iy<HH && ix>=0 && ix<WW) v=inb[((size_t)ci*HH+iy)*WW+ix];
      rows[r][kx]=v;
    }
    for (int e=tid; e<288; e+=256) {
      int c=e/9, kk=e%9;
      wl[e] = w[((size_t)(ch*32+c)*CIN + ci)*9 + kk];
    }
    __syncthreads();
    float wr[9];
    #pragma unroll
    for (int u=0;u<9;u++) wr[u]=wl[lco*9+u];
    #pragma unroll
    for (int r=0;r<3;r++) {
      #pragma unroll
      for (int i=0;i<12;i++) {
        acc[i]=fmaf(wr[r*3+0], rows[r][xb+i],   acc[i]);
        acc[i]=fmaf(wr[r*3+1], rows[r][xb+i+1], acc[i]);
        acc[i]=fmaf(wr[r*3+2], rows[r][xb+i+2], acc[i]);
      }
    }
  }
  if (relu) {
    #pragma unroll
    for (int i=0;i<12;i++) acc[i]=fmaxf(acc[i],0.f);
  }
  if (tr) {  // token-major [n][t][couts]
    #pragma unroll
    for (int i=0;i<12;i++)
      out[((size_t)n*LTOK + oy*WW + xb+i)*couts + co] = acc[i];
  } else {   // NCHW
    float4* op = (float4*)(out + ((size_t)(n*couts+co)*HH + oy)*WW + xb);
    op[0]=make_float4(acc[0],acc[1],acc[2],acc[3]);
    op[1]=make_float4(acc[4],acc[5],acc[6],acc[7]);
    op[2]=make_float4(acc[8],acc[9],acc[10],acc[11]);
  }
}

// ---------------- 1x1 conv as LDS-tiled GEMM: 64co x 128tok x 64ci per block ----------------
__global__ __launch_bounds__(256) void k_conv1x1(const float* __restrict__ in, const float* __restrict__ w,
                          const float* __restrict__ bias, float* __restrict__ out) {
  int blk = blockIdx.x;           // NB * 72
  int n  = blk / (LTOK/128);
  int t0 = (blk % (LTOK/128)) * 128;
  int tid = threadIdx.x;
  __shared__ float Wl[64*64];     // [ci][co]
  __shared__ float Xl[64][128];
  for (int e=tid; e<4096; e+=256) {
    int ci=e>>6, co=e&63;
    Wl[e] = w[co*CIN + ci];       // transposed store; one-time
  }
  for (int e=tid; e<64*128; e+=256) {
    int ci=e>>7, t=e&127;
    Xl[ci][t] = in[(size_t)n*CIN*LTOK + (size_t)ci*LTOK + t0 + t];
  }
  __syncthreads();
  int co = tid & 63, tg = tid >> 6;   // tg uniform per wave
  float acc[32];
  float bv = bias[co];
  #pragma unroll
  for (int i=0;i<32;i++) acc[i]=bv;
  for (int ci=0;ci<64;ci++){
    float wv = Wl[ci*64+co];
    const float4* xr = (const float4*)&Xl[ci][tg*32];
    #pragma unroll
    for (int r=0;r<8;r++){
      float4 xv = xr[r];
      acc[4*r+0]=fmaf(wv,xv.x,acc[4*r+0]);
      acc[4*r+1]=fmaf(wv,xv.y,acc[4*r+1]);
      acc[4*r+2]=fmaf(wv,xv.z,acc[4*r+2]);
      acc[4*r+3]=fmaf(wv,xv.w,acc[4*r+3]);
    }
  }
  float* ob = out + ((size_t)n*LTOK + t0 + tg*32)*CO + co;
  #pragma unroll
  for (int i=0;i<32;i++) ob[(size_t)i*CO] = acc[i];
}

// ---------------- LSH hash: codes + per-block histogram (block-uniform h since 9216=18*512) --
__global__ void k_hash(const float* __restrict__ xe, const float* __restrict__ rot,
                       int* __restrict__ codes, int* __restrict__ hist) {
  int b  = blockIdx.x;           // 0..NB*NSB-1
  int n  = b / NSB;
  int bb = b % NSB;
  int j  = bb*SB + threadIdx.x;  // 0..TOT-1
  int h  = j / LTOK;             // uniform within block
  int t  = j % LTOK;
  __shared__ float rl[CM][NBUCK/2];
  __shared__ int lh[256];
  for (int e = threadIdx.x; e < 256; e += SB) lh[e] = 0;
  for (int e = threadIdx.x; e < CM*(NBUCK/2); e += SB) {
    int f = e / 32, i = e % 32;
    rl[f][i] = rot[(f*NH + h)*32 + i];
  }
  __syncthreads();
  float q[CM];
  const float4* xr4 = (const float4*)(xe + ((size_t)n*LTOK + t)*CM);
  #pragma unroll
  for (int r = 0; r < 8; r++) {
    float4 v = xr4[r];
    q[4*r+0]=v.x; q[4*r+1]=v.y; q[4*r+2]=v.z; q[4*r+3]=v.w;
  }
  float bp = -INFINITY, bn = -INFINITY; int ip = 0, inn = 0;
  for (int i = 0; i < 32; i++) {
    float acc = 0.f;
    #pragma unroll
    for (int f = 0; f < CM; f++) acc = fmaf(q[f], rl[f][i], acc);
    if (acc  > bp) { bp = acc;  ip  = i; }
    if (-acc > bn) { bn = -acc; inn = i; }
  }
  int code = (bp >= bn) ? ip : (32 + inn);   // first-occurrence tie-break: positives first
  code += h * NBUCK;
  codes[n*TOT + j] = code;
  atomicAdd(&lh[code], 1);
  __syncthreads();
  for (int e = threadIdx.x; e < 256; e += SB) hist[((size_t)(n*NSB + bb))*256 + e] = lh[e];
}

// ---------------- stable counting sort: code totals scan + per-block starts ----------------
__global__ void k_offsets(const int* __restrict__ hist, int* __restrict__ bstart) {
  int n = blockIdx.x; int c = threadIdx.x;    // 256 threads
  int tot = 0;
  for (int b = 0; b < NSB; b++) tot += hist[((size_t)(n*NSB + b))*256 + c];
  __shared__ int sc[256];
  sc[c] = tot;
  __syncthreads();
  for (int d = 1; d < 256; d <<= 1) {
    int u = (c >= d) ? sc[c-d] : 0;
    __syncthreads();
    sc[c] += u;
    __syncthreads();
  }
  int run = sc[c] - tot;   // exclusive prefix over codes
  for (int b = 0; b < NSB; b++) {
    bstart[((size_t)(n*NSB + b))*256 + c] = run;
    run += hist[((size_t)(n*NSB + b))*256 + c];
  }
}

__global__ void k_scatter(const int* __restrict__ codes, const int* __restrict__ bstart,
                          int* __restrict__ sidx) {
  int b = blockIdx.x; int n = b / NSB; int bb = b % NSB;
  int j = bb*SB + threadIdx.x;
  int code = codes[n*TOT + j];
  __shared__ unsigned char lc[SB];
  lc[threadIdx.x] = (unsigned char)code;
  __syncthreads();
  int rank = 0;
  unsigned char my = (unsigned char)code;
  for (int e = 0; e < threadIdx.x; e++) rank += (lc[e] == my) ? 1 : 0;
  int pos = bstart[((size_t)(n*NSB + bb))*256 + code] + rank;
  sidx[n*TOT + pos] = j;    // idx[s] = original flat index (h*L + t)
}

// ---------------- MFMA bf16 flash attention over LSH chunks ---------------------------------
// block = 192 thr (3 waves); wave w owns query rows 48w..48w+47 of the chunk.
// m = ||q|| exactly (self-key in chunk, cos<=1) -> no online rescale.
#define QP 40    // Q/K row pitch in shorts (80B, 16B-aligned)
#define PP 104   // P / V^T row pitch in shorts (208B, 16B-aligned)
__global__ __launch_bounds__(192,1) void k_attn(const float* __restrict__ xe, const float* __restrict__ ye,
                       const int* __restrict__ sidx, float* __restrict__ ret,
                       float* __restrict__ bsc) {
  int blk = blockIdx.x;               // 1024 = NB*NH*NCHUNK
  int kch = blk % NCHUNK;
  int h = (blk / NCHUNK) % NH;
  int n = blk / (NCHUNK*NH);
  const int base = n*TOT + h*LTOK;    // into sidx
  __shared__ __align__(16) short Pq[144*PP];   // P (bf16); prologue: Q rows at pitch QP
  __shared__ __align__(16) short Kb[96*QP];    // normalized keys bf16 [key][32]
  __shared__ __align__(16) short VbT[64*PP];   // V^T bf16 [ch][key]
  __shared__ float qn[144];
  int tid = threadIdx.x;
  int w = tid >> 6, lane = tid & 63, quad = lane >> 4, l16 = lane & 15;

  // ---- prologue: stage Q (bf16, unnormalized) + qn = ||q|| ----
  if (tid < 144) {
    int tok = sidx[base + kch*CHUNK + tid] % LTOK;
    const float4* qr = (const float4*)(xe + ((size_t)n*LTOK + tok)*CM);
    float ssq = 0.f; short8 s8[4];
    #pragma unroll
    for (int r=0;r<8;r++) {
      float4 v = qr[r];
      ssq = fmaf(v.x,v.x,ssq); ssq = fmaf(v.y,v.y,ssq);
      ssq = fmaf(v.z,v.z,ssq); ssq = fmaf(v.w,v.w,ssq);
      s8[r>>1][4*(r&1)+0]=f2bf(v.x); s8[r>>1][4*(r&1)+1]=f2bf(v.y);
      s8[r>>1][4*(r&1)+2]=f2bf(v.z); s8[r>>1][4*(r&1)+3]=f2bf(v.w);
    }
    qn[tid] = sqrtf(ssq);
    #pragma unroll
    for (int r=0;r<4;r++) *(short8*)&Pq[tid*QP + 8*r] = s8[r];
  }
  __syncthreads();
  short8 qfrag[3];
  float m_ln[3][4];
  #pragma unroll
  for (int t=0;t<3;t++) {
    qfrag[t] = *(short8*)&Pq[(48*w + 16*t + l16)*QP + quad*8];
    #pragma unroll
    for (int r=0;r<4;r++) m_ln[t][r] = qn[48*w + 16*t + 4*quad + r];
  }
  f32x4 acc[3][4];
  #pragma unroll
  for (int mt=0;mt<3;mt++)
    #pragma unroll
    for (int nt=0;nt<4;nt++) acc[mt][nt] = (f32x4){0.f,0.f,0.f,0.f};
  float sspart[12];
  #pragma unroll
  for (int i=0;i<12;i++) sspart[i]=0.f;

  for (int tt = 0; tt < 3; tt++) {
    int kk = (tt == 0) ? kch : ((tt == 1) ? (kch + NCHUNK - 1) % NCHUNK : (kch + 1) % NCHUNK);
    for (int hh = 0; hh < 2; hh++) {
      int off = hh ? 96 : 0;
      int KC  = hh ? 48 : 96;       // keys this sub-tile
      int NT  = hh ? 3  : 6;        // S n-tiles (16 keys each)
      int KF  = hh ? 2  : 3;        // PV k-frags (32 keys each; hh=1 cols 48..63 zero-pad)
      __syncthreads();   // previous sub-tile fully consumed (and prologue Q-frag reads done)
      // stage K: one thread per key row, fp32 norm then bf16
      if (tid < KC) {
        int tok = sidx[base + kk*CHUNK + off + tid] % LTOK;
        const float4* kr = (const float4*)(xe + ((size_t)n*LTOK + tok)*CM);
        float ssq = 0.f; float vv[32];
        #pragma unroll
        for (int r=0;r<8;r++) {
          float4 v = kr[r];
          vv[4*r]=v.x; vv[4*r+1]=v.y; vv[4*r+2]=v.z; vv[4*r+3]=v.w;
          ssq = fmaf(v.x,v.x,ssq); ssq = fmaf(v.y,v.y,ssq);
          ssq = fmaf(v.z,v.z,ssq); ssq = fmaf(v.w,v.w,ssq);
        }
        float rn = 1.f / fmaxf(sqrtf(ssq), 5e-5f);
        #pragma unroll
        for (int r=0;r<4;r++) {
          short8 s8;
          #pragma unroll
          for (int j=0;j<8;j++) s8[j] = f2bf(vv[8*r+j]*rn);
          *(short8*)&Kb[tid*QP + 8*r] = s8;
        }
      }
      // stage V transposed: task = (chgroup g of 4, key); key contiguous across threads
      int ntask = KC*16, nit = ntask/192;
      for (int it=0; it<nit; it++) {
        int idx = tid + 192*it;
        int g = idx / KC, key = idx - g*KC;
        int tok = sidx[base + kk*CHUNK + off + key] % LTOK;
        float4 v = *(const float4*)(ye + ((size_t)n*LTOK + tok)*CO + 4*g);
        VbT[(4*g+0)*PP + key] = f2bf(v.x);
        VbT[(4*g+1)*PP + key] = f2bf(v.y);
        VbT[(4*g+2)*PP + key] = f2bf(v.z);
        VbT[(4*g+3)*PP + key] = f2bf(v.w);
      }
      __syncthreads();
      if (hh == 1 && lane < 48) {   // zero P cols 48..63 (pad for last k-frag); wave-private rows
        int row = 48*w + lane;
        *(short8*)&Pq[row*PP + 48] = (short8){0,0,0,0,0,0,0,0};
        *(short8*)&Pq[row*PP + 56] = (short8){0,0,0,0,0,0,0,0};
      }
      // ---- S = Q . K^T, exp, write P (bf16, A-frag layout), accumulate row sums ----
      for (int nt = 0; nt < NT; nt++) {
        short8 bfr = *(short8*)&Kb[(16*nt + l16)*QP + quad*8];
        f32x4 c[3];
        #pragma unroll
        for (int mt=0;mt<3;mt++)
          c[mt] = __builtin_amdgcn_mfma_f32_16x16x32_bf16(qfrag[mt], bfr, (f32x4){0.f,0.f,0.f,0.f}, 0, 0, 0);
        #pragma unroll
        for (int mt=0;mt<3;mt++) {
          #pragma unroll
          for (int reg=0;reg<4;reg++) {
            float p = __expf(c[mt][reg] - m_ln[mt][reg]);
            sspart[mt*4+reg] += p;
            int row = 48*w + 16*mt + 4*quad + reg;
            Pq[row*PP + 16*nt + l16] = f2bf(p);
          }
        }
      }
      // ---- PV: ret += P . V ----
      for (int kf = 0; kf < KF; kf++) {
        short8 afr[3];
        #pragma unroll
        for (int mt=0;mt<3;mt++)
          afr[mt] = *(short8*)&Pq[(48*w + 16*mt + l16)*PP + kf*32 + quad*8];
        #pragma unroll
        for (int nt2=0;nt2<4;nt2++) {
          short8 vfr = *(short8*)&VbT[(16*nt2 + l16)*PP + kf*32 + quad*8];
          #pragma unroll
          for (int mt=0;mt<3;mt++)
            acc[mt][nt2] = __builtin_amdgcn_mfma_f32_16x16x32_bf16(afr[mt], vfr, acc[mt][nt2], 0, 0, 0);
        }
      }
    }
  }
  // ---- epilogue: reduce row sums over the 16 cols (lanes l16), normalize, scatter ----
  #pragma unroll
  for (int i=0;i<12;i++) {
    float v = sspart[i];
    v += __shfl_xor(v, 1); v += __shfl_xor(v, 2);
    v += __shfl_xor(v, 4); v += __shfl_xor(v, 8);
    sspart[i] = v;
  }
  #pragma unroll
  for (int mt=0;mt<3;mt++) {
    #pragma unroll
    for (int reg=0;reg<4;reg++) {
      int row = 48*w + 16*mt + 4*quad + reg;
      int mtok = sidx[base + kch*CHUNK + row];     // full index h*L+t
      float ssum = sspart[mt*4+reg];
      float inv = 1.f / ssum;
      float* rp = ret + ((size_t)n*TOT + mtok)*CO;
      #pragma unroll
      for (int nt2=0;nt2<4;nt2++) rp[16*nt2 + l16] = acc[mt][nt2][reg] * inv;
      if (l16 == 0) bsc[(size_t)n*TOT + mtok] = m_ln[mt][reg] + logf(ssum);
    }
  }
}

// ---------------- combine 4 hash rounds (softmax over bscore) + residual, NCHW out ----------
__global__ void k_combine(const float* __restrict__ ret, const float* __restrict__ bsc,
                          const float* __restrict__ c2, float* __restrict__ out) {
  int blk = blockIdx.x;                 // NB * (LTOK/16)
  int n  = blk / (LTOK/16);
  int t0 = (blk % (LTOK/16)) * 16;
  __shared__ float rl[NH][16][CO+1];
  __shared__ float pw[NH][16];
  int tid = threadIdx.x;
  for (int h = 0; h < NH; h++)
    for (int e = tid; e < 16*CO; e += 256) {
      int tl = e >> 6, f = e & 63;
      rl[h][tl][f] = ret[((size_t)n*TOT + h*LTOK + t0 + tl)*CO + f];
    }
  if (tid < 16) {
    float b0[NH]; float mm = -INFINITY;
    #pragma unroll
    for (int h = 0; h < NH; h++) { b0[h] = bsc[(size_t)n*TOT + h*LTOK + t0 + tid]; mm = fmaxf(mm, b0[h]); }
    float s = 0.f;
    #pragma unroll
    for (int h = 0; h < NH; h++) { b0[h] = __expf(b0[h] - mm); s += b0[h]; }
    float inv = 1.f / s;
    #pragma unroll
    for (int h = 0; h < NH; h++) pw[h][tid] = b0[h] * inv;
  }
  __syncthreads();
  int tl = tid & 15;
  int cog = tid >> 4;     // 0..15
  #pragma unroll
  for (int cc = 0; cc < 4; cc++) {
    int co = cog + 16*cc;
    size_t oi = ((size_t)(n*CO + co))*LTOK + t0 + tl;
    float a = c2[oi];
    #pragma unroll
    for (int h = 0; h < NH; h++) a = fmaf(pw[h][tl], rl[h][tl][co], a);
    out[oi] = a;
  }
}

extern "C" void kernel_launch(void* const* d_in, const int* in_sizes, int n_in,
                              void* d_out, int out_size, void* d_ws, size_t ws_size,
                              hipStream_t stream) {
  const float* x   = (const float*)d_in[0];
  const float* w1  = (const float*)d_in[1];
  const float* b1  = (const float*)d_in[2];
  const float* w2  = (const float*)d_in[3];
  const float* b2  = (const float*)d_in[4];
  const float* wm  = (const float*)d_in[5];
  const float* bm  = (const float*)d_in[6];
  const float* wa  = (const float*)d_in[7];
  const float* ba  = (const float*)d_in[8];
  const float* rot = (const float*)d_in[9];
  float* out = (float*)d_out;

  float* ws  = (float*)d_ws;
  float* up  = ws;                    // 2359296
  float* c1  = up  + 2359296;         // 2359296
  float* c2  = c1  + 2359296;         // 2359296
  float* xep = c2  + 2359296;         // 1179648  [n][t][32]
  float* yep = xep + 1179648;         // 2359296  [n][t][64]
  float* bsc = yep + 2359296;         // 147456   [n][h*L+t]
  float* ret = bsc + 147456;          // 9437184  [n][h*L+t][64]
  int* codes  = (int*)(ret + 9437184);// 147456
  int* sidx   = codes + 147456;       // 147456
  int* hist   = sidx + 147456;        // 73728
  int* bstart = hist + 73728;         // 73728
  (void)in_sizes; (void)n_in; (void)out_size; (void)ws_size;

  k_upsample<<<dim3((NB*CIN*HH*WW + 255)/256), dim3(256), 0, stream>>>(x, up);
  k_conv3<<<dim3(NB*HH*2), dim3(256), 0, stream>>>(up, w1, b1, c1, CO, 1, 0, 2);
  k_conv3<<<dim3(NB*HH*2), dim3(256), 0, stream>>>(c1, w2, b2, c2, CO, 1, 0, 2);
  k_conv3<<<dim3(NB*HH*1), dim3(256), 0, stream>>>(c2, wm, bm, xep, CM, 0, 1, 1);
  k_conv1x1<<<dim3(NB*(LTOK/128)), dim3(256), 0, stream>>>(c2, wa, ba, yep);
  k_hash<<<dim3(NB*NSB), dim3(SB), 0, stream>>>(xep, rot, codes, hist);
  k_offsets<<<dim3(NB), dim3(256), 0, stream>>>(hist, bstart);
  k_scatter<<<dim3(NB*NSB), dim3(SB), 0, stream>>>(codes, bstart, sidx);
  k_attn<<<dim3(NB*NH*NCHUNK), dim3(192), 0, stream>>>(xep, yep, sidx, ret, bsc);
  k_combine<<<dim3(NB*(LTOK/16)), dim3(256), 0, stream>>>(ret, bsc, c2, out);
}

// Round 4
// 405.334 us; speedup vs baseline: 4.7387x; 1.3677x over previous
//
#include <hip/hip_runtime.h>
#include <math.h>

#define NB 4
#define CIN 64
#define CO 64
#define CM 32
#define H0 48
#define W0 48
#define HH 96
#define WW 96
#define LTOK (HH*WW)     // 9216 tokens per image
#define NH 4
#define NBUCK 64
#define CHUNK 144
#define NCHUNK 64        // LTOK / CHUNK
#define TOT (NH*LTOK)    // 36864
#define SB 512
#define NSB (TOT/SB)     // 72

typedef __attribute__((ext_vector_type(8))) short short8;
typedef __attribute__((ext_vector_type(4))) short short4v;
typedef __attribute__((ext_vector_type(4))) float f32x4;

__device__ __forceinline__ short f2bf(float f) {
  union { float f; unsigned u; } v; v.f = f;
  unsigned r = v.u + 0x7fffu + ((v.u >> 16) & 1u);
  return (short)(r >> 16);
}
__device__ __forceinline__ float bf2f(short h) {
  union { float f; unsigned u; } v; v.u = ((unsigned)(unsigned short)h) << 16;
  return v.f;
}
__device__ __forceinline__ short8 ld_b64x2(const short* p) {  // 8B-aligned pair load
  short4v a = *(const short4v*)p;
  short4v b = *(const short4v*)(p+4);
  short8 r; r[0]=a[0];r[1]=a[1];r[2]=a[2];r[3]=a[3];r[4]=b[0];r[5]=b[1];r[6]=b[2];r[7]=b[3];
  return r;
}

// ---------------- bicubic upsample (jax.image.resize, cubic a=-0.5, half-pixel) ----------------
__device__ __forceinline__ void cubic_taps(int o, int insz, int* p, float* w) {
  int j = o >> 1;
  const float B0=-0.0234375f, B1=0.2265625f, B2=0.8671875f, B3=-0.0703125f;
  if ((o & 1) == 0) { p[0]=j-2;p[1]=j-1;p[2]=j;  p[3]=j+1; w[0]=B0;w[1]=B1;w[2]=B2;w[3]=B3; }
  else              { p[0]=j-1;p[1]=j;  p[2]=j+1;p[3]=j+2; w[0]=B3;w[1]=B2;w[2]=B1;w[3]=B0; }
  float s = 0.f;
  #pragma unroll
  for (int a=0;a<4;a++){ if (p[a] < 0 || p[a] >= insz) p[a] = -1; else s += w[a]; }
  float inv = 1.f / s;
  #pragma unroll
  for (int a=0;a<4;a++) w[a] *= inv;
}

__global__ void k_upsample(const float* __restrict__ x, float* __restrict__ up) {
  int i = blockIdx.x*blockDim.x + threadIdx.x;
  if (i >= NB*CIN*HH*WW) return;
  int ox = i % WW; int t = i / WW;
  int oy = t % HH; t /= HH;
  int c = t % CIN; int n = t / CIN;
  int px[4]; float wx[4]; cubic_taps(ox, W0, px, wx);
  int py[4]; float wy[4]; cubic_taps(oy, H0, py, wy);
  const float* src = x + ((size_t)(n*CIN + c))*H0*W0;
  float acc = 0.f;
  #pragma unroll
  for (int a=0;a<4;a++) {
    if (py[a] < 0) continue;
    const float* r = src + py[a]*W0;
    float ra = 0.f;
    #pragma unroll
    for (int b=0;b<4;b++) if (px[b] >= 0) ra = fmaf(wx[b], r[px[b]], ra);
    acc = fmaf(wy[a], ra, acc);
  }
  up[i] = acc;
}

// ---------------- weight prep: fp32 [co][ci][3][3] -> bf16 hi/lo planes [s][co][ci] ----------
__global__ void k_wprep(const float* __restrict__ w, short* __restrict__ dH,
                        short* __restrict__ dL, int couts) {
  int i = blockIdx.x*blockDim.x + threadIdx.x;
  int n = 9*couts*64;
  if (i >= n) return;
  int ci = i & 63; int t = i >> 6; int co = t % couts; int s = t / couts;
  float v = w[((size_t)(co*64 + ci))*9 + s];
  short hi = f2bf(v);
  dH[i] = hi;
  dL[i] = f2bf(v - bf2f(hi));
}

// ---------------- 3x3 conv as implicit GEMM over 9 shifts, bf16 MFMA (W split hi/lo) --------
// block = 256 thr (4 waves), 128 tokens x COUTS. 18 K-stages (9 shifts x 2 ci-halves, K=32).
#define XP 36   // X LDS pitch in shorts (72B: 8B-aligned b64 frag reads, conflict-free)
#define WP 40   // W LDS pitch in shorts (80B: 16B-aligned b128 reads, 2-way free)
template<int COUTS, bool TMAJ, bool RELU>
__global__ __launch_bounds__(256) void k_conv3m(const float* __restrict__ in,
                          const short* __restrict__ wH, const short* __restrict__ wL,
                          const float* __restrict__ bias, float* __restrict__ out) {
  int blk = blockIdx.x;              // NB*72
  int n  = blk / 72;
  int t0 = (blk % 72) * 128;
  int tid = threadIdx.x;
  int wv = tid >> 6, lane = tid & 63, quad = lane >> 4, l16 = lane & 15;
  __shared__ __align__(16) short XB[128*XP];
  __shared__ __align__(16) short WHs[COUTS*WP];
  __shared__ __align__(16) short WLs[COUTS*WP];
  __shared__ float biasl[COUTS];
  if (tid < COUTS) biasl[tid] = bias[tid];
  const int MT = TMAJ ? 2 : 4;       // m-frags: tokens(2) or co(4)
  const int NWT = COUTS/16;          // n-frags over the non-token dim when TMAJ
  f32x4 acc[4][2];
  #pragma unroll
  for (int a=0;a<4;a++)
    #pragma unroll
    for (int b=0;b<2;b++) acc[a][b] = (f32x4){0.f,0.f,0.f,0.f};

  const float* inb = in + (size_t)n*CIN*LTOK;
  for (int s = 0; s < 9; s++) {
    int dy = s/3 - 1, dx = s%3 - 1;
    for (int cih = 0; cih < 2; cih++) {
      __syncthreads();   // previous stage fully consumed
      // ---- stage X: 128 tok x 32 ci (bf16, dword-packed ci pairs) ----
      #pragma unroll
      for (int it = 0; it < 8; it++) {
        int idx = tid + 256*it;            // 2048 tasks
        int tok = idx & 127, c = idx >> 7; // c in [0,16): ci pair {2c,2c+1}
        int t = t0 + tok;
        int y = t / WW, x = t - y*WW;
        int ys = y + dy, xs = x + dx;
        float v0 = 0.f, v1 = 0.f;
        if ((unsigned)ys < HH && (unsigned)xs < WW) {
          const float* p = inb + ((size_t)(cih*32 + 2*c))*LTOK + ys*WW + xs;
          v0 = p[0]; v1 = p[LTOK];
        }
        unsigned pk = (unsigned)(unsigned short)f2bf(v0) | (((unsigned)(unsigned short)f2bf(v1)) << 16);
        ((unsigned*)XB)[tok*(XP/2) + c] = pk;
      }
      // ---- stage W hi/lo: COUTS x 32 ci (dword-packed) ----
      #pragma unroll
      for (int it = 0; it < (COUTS*32)/(2*256); it++) {
        int idx = tid + 256*it;            // COUTS*16 tasks
        int co = idx >> 4, cp = idx & 15;
        int gsrc = ((s*COUTS + co)*64 + cih*32) >> 1;
        ((unsigned*)WHs)[co*(WP/2) + cp] = ((const unsigned*)wH)[gsrc + cp];
        ((unsigned*)WLs)[co*(WP/2) + cp] = ((const unsigned*)wL)[gsrc + cp];
      }
      __syncthreads();
      // ---- MFMA ----
      if (!TMAJ) {
        // D[m=co][n=tok]: A = W (hi then lo), B = X
        short8 xf[2];
        #pragma unroll
        for (int nt=0;nt<2;nt++)
          xf[nt] = ld_b64x2(&XB[(wv*32 + nt*16 + l16)*XP + quad*8]);
        #pragma unroll
        for (int mt=0;mt<4;mt++) {
          short8 wh = *(const short8*)&WHs[(mt*16 + l16)*WP + quad*8];
          short8 wl = *(const short8*)&WLs[(mt*16 + l16)*WP + quad*8];
          #pragma unroll
          for (int nt=0;nt<2;nt++) {
            acc[mt][nt] = __builtin_amdgcn_mfma_f32_16x16x32_bf16(wh, xf[nt], acc[mt][nt], 0, 0, 0);
            acc[mt][nt] = __builtin_amdgcn_mfma_f32_16x16x32_bf16(wl, xf[nt], acc[mt][nt], 0, 0, 0);
          }
        }
      } else {
        // D[m=tok][n=co]: A = X, B = W (hi then lo)
        short8 xf[2];
        #pragma unroll
        for (int mt=0;mt<MT;mt++)
          xf[mt] = ld_b64x2(&XB[(wv*32 + mt*16 + l16)*XP + quad*8]);
        #pragma unroll
        for (int nt=0;nt<NWT;nt++) {
          short8 wh = *(const short8*)&WHs[(nt*16 + l16)*WP + quad*8];
          short8 wl = *(const short8*)&WLs[(nt*16 + l16)*WP + quad*8];
          #pragma unroll
          for (int mt=0;mt<MT;mt++) {
            acc[mt][nt] = __builtin_amdgcn_mfma_f32_16x16x32_bf16(xf[mt], wh, acc[mt][nt], 0, 0, 0);
            acc[mt][nt] = __builtin_amdgcn_mfma_f32_16x16x32_bf16(xf[mt], wl, acc[mt][nt], 0, 0, 0);
          }
        }
      }
    }
  }
  // ---- epilogue ----
  if (!TMAJ) {
    #pragma unroll
    for (int mt=0;mt<4;mt++) {
      #pragma unroll
      for (int nt=0;nt<2;nt++) {
        int tokl = wv*32 + nt*16 + l16;
        #pragma unroll
        for (int reg=0;reg<4;reg++) {
          int co = mt*16 + quad*4 + reg;
          float v = acc[mt][nt][reg] + biasl[co];
          if (RELU) v = fmaxf(v, 0.f);
          out[((size_t)(n*COUTS + co))*LTOK + t0 + tokl] = v;
        }
      }
    }
  } else {
    #pragma unroll
    for (int mt=0;mt<MT;mt++) {
      #pragma unroll
      for (int nt=0;nt<NWT;nt++) {
        int co = nt*16 + l16;
        #pragma unroll
        for (int reg=0;reg<4;reg++) {
          int t = t0 + wv*32 + mt*16 + quad*4 + reg;
          float v = acc[mt][nt][reg] + biasl[co];
          if (RELU) v = fmaxf(v, 0.f);
          out[((size_t)n*LTOK + t)*COUTS + co] = v;
        }
      }
    }
  }
}

// ---------------- 1x1 conv as LDS-tiled GEMM: 64co x 128tok x 64ci per block ----------------
__global__ __launch_bounds__(256) void k_conv1x1(const float* __restrict__ in, const float* __restrict__ w,
                          const float* __restrict__ bias, float* __restrict__ out) {
  int blk = blockIdx.x;           // NB * 72
  int n  = blk / (LTOK/128);
  int t0 = (blk % (LTOK/128)) * 128;
  int tid = threadIdx.x;
  __shared__ float Wl[64*64];     // [ci][co]
  __shared__ float Xl[64][128];
  for (int e=tid; e<4096; e+=256) {
    int ci=e>>6, co=e&63;
    Wl[e] = w[co*CIN + ci];       // transposed store; one-time
  }
  for (int e=tid; e<64*128; e+=256) {
    int ci=e>>7, t=e&127;
    Xl[ci][t] = in[(size_t)n*CIN*LTOK + (size_t)ci*LTOK + t0 + t];
  }
  __syncthreads();
  int co = tid & 63, tg = tid >> 6;   // tg uniform per wave
  float acc[32];
  float bv = bias[co];
  #pragma unroll
  for (int i=0;i<32;i++) acc[i]=bv;
  for (int ci=0;ci<64;ci++){
    float wv = Wl[ci*64+co];
    const float4* xr = (const float4*)&Xl[ci][tg*32];
    #pragma unroll
    for (int r=0;r<8;r++){
      float4 xv = xr[r];
      acc[4*r+0]=fmaf(wv,xv.x,acc[4*r+0]);
      acc[4*r+1]=fmaf(wv,xv.y,acc[4*r+1]);
      acc[4*r+2]=fmaf(wv,xv.z,acc[4*r+2]);
      acc[4*r+3]=fmaf(wv,xv.w,acc[4*r+3]);
    }
  }
  float* ob = out + ((size_t)n*LTOK + t0 + tg*32)*CO + co;
  #pragma unroll
  for (int i=0;i<32;i++) ob[(size_t)i*CO] = acc[i];
}

// ---------------- LSH hash: codes + per-block histogram (block-uniform h since 9216=18*512) --
__global__ void k_hash(const float* __restrict__ xe, const float* __restrict__ rot,
                       int* __restrict__ codes, int* __restrict__ hist) {
  int b  = blockIdx.x;           // 0..NB*NSB-1
  int n  = b / NSB;
  int bb = b % NSB;
  int j  = bb*SB + threadIdx.x;  // 0..TOT-1
  int h  = j / LTOK;             // uniform within block
  int t  = j % LTOK;
  __shared__ float rl[CM][NBUCK/2];
  __shared__ int lh[256];
  for (int e = threadIdx.x; e < 256; e += SB) lh[e] = 0;
  for (int e = threadIdx.x; e < CM*(NBUCK/2); e += SB) {
    int f = e / 32, i = e % 32;
    rl[f][i] = rot[(f*NH + h)*32 + i];
  }
  __syncthreads();
  float q[CM];
  const float4* xr4 = (const float4*)(xe + ((size_t)n*LTOK + t)*CM);
  #pragma unroll
  for (int r = 0; r < 8; r++) {
    float4 v = xr4[r];
    q[4*r+0]=v.x; q[4*r+1]=v.y; q[4*r+2]=v.z; q[4*r+3]=v.w;
  }
  float bp = -INFINITY, bn = -INFINITY; int ip = 0, inn = 0;
  for (int i = 0; i < 32; i++) {
    float acc = 0.f;
    #pragma unroll
    for (int f = 0; f < CM; f++) acc = fmaf(q[f], rl[f][i], acc);
    if (acc  > bp) { bp = acc;  ip  = i; }
    if (-acc > bn) { bn = -acc; inn = i; }
  }
  int code = (bp >= bn) ? ip : (32 + inn);   // first-occurrence tie-break: positives first
  code += h * NBUCK;
  codes[n*TOT + j] = code;
  atomicAdd(&lh[code], 1);
  __syncthreads();
  for (int e = threadIdx.x; e < 256; e += SB) hist[((size_t)(n*NSB + bb))*256 + e] = lh[e];
}

// ---------------- stable counting sort: code totals scan + per-block starts ----------------
__global__ void k_offsets(const int* __restrict__ hist, int* __restrict__ bstart) {
  int n = blockIdx.x; int c = threadIdx.x;    // 256 threads
  int tot = 0;
  for (int b = 0; b < NSB; b++) tot += hist[((size_t)(n*NSB + b))*256 + c];
  __shared__ int sc[256];
  sc[c] = tot;
  __syncthreads();
  for (int d = 1; d < 256; d <<= 1) {
    int u = (c >= d) ? sc[c-d] : 0;
    __syncthreads();
    sc[c] += u;
    __syncthreads();
  }
  int run = sc[c] - tot;   // exclusive prefix over codes
  for (int b = 0; b < NSB; b++) {
    bstart[((size_t)(n*NSB + b))*256 + c] = run;
    run += hist[((size_t)(n*NSB + b))*256 + c];
  }
}

__global__ void k_scatter(const int* __restrict__ codes, const int* __restrict__ bstart,
                          int* __restrict__ sidx) {
  int b = blockIdx.x; int n = b / NSB; int bb = b % NSB;
  int j = bb*SB + threadIdx.x;
  int code = codes[n*TOT + j];
  __shared__ unsigned char lc[SB];
  lc[threadIdx.x] = (unsigned char)code;
  __syncthreads();
  int rank = 0;
  unsigned char my = (unsigned char)code;
  for (int e = 0; e < threadIdx.x; e++) rank += (lc[e] == my) ? 1 : 0;
  int pos = bstart[((size_t)(n*NSB + bb))*256 + code] + rank;
  sidx[n*TOT + pos] = j;    // idx[s] = original flat index (h*L + t)
}

// ---------------- MFMA bf16 flash attention over LSH chunks ---------------------------------
// block = 192 thr (3 waves); wave w owns query rows 48w..48w+47 of the chunk.
// m = ||q|| exactly (self-key in chunk, cos<=1) -> no online rescale.
#define QP 40    // Q/K row pitch in shorts (80B, 16B-aligned)
#define PP 104   // P / V^T row pitch in shorts (208B, 16B-aligned)
__global__ __launch_bounds__(192,1) void k_attn(const float* __restrict__ xe, const float* __restrict__ ye,
                       const int* __restrict__ sidx, float* __restrict__ ret,
                       float* __restrict__ bsc) {
  int blk = blockIdx.x;               // 1024 = NB*NH*NCHUNK
  int kch = blk % NCHUNK;
  int h = (blk / NCHUNK) % NH;
  int n = blk / (NCHUNK*NH);
  const int base = n*TOT + h*LTOK;    // into sidx
  __shared__ __align__(16) short Pq[144*PP];   // P (bf16); prologue: Q rows at pitch QP
  __shared__ __align__(16) short Kb[96*QP];    // normalized keys bf16 [key][32]
  __shared__ __align__(16) short VbT[64*PP];   // V^T bf16 [ch][key]
  __shared__ float qn[144];
  int tid = threadIdx.x;
  int w = tid >> 6, lane = tid & 63, quad = lane >> 4, l16 = lane & 15;

  // ---- prologue: stage Q (bf16, unnormalized) + qn = ||q|| ----
  if (tid < 144) {
    int tok = sidx[base + kch*CHUNK + tid] % LTOK;
    const float4* qr = (const float4*)(xe + ((size_t)n*LTOK + tok)*CM);
    float ssq = 0.f; short8 s8[4];
    #pragma unroll
    for (int r=0;r<8;r++) {
      float4 v = qr[r];
      ssq = fmaf(v.x,v.x,ssq); ssq = fmaf(v.y,v.y,ssq);
      ssq = fmaf(v.z,v.z,ssq); ssq = fmaf(v.w,v.w,ssq);
      s8[r>>1][4*(r&1)+0]=f2bf(v.x); s8[r>>1][4*(r&1)+1]=f2bf(v.y);
      s8[r>>1][4*(r&1)+2]=f2bf(v.z); s8[r>>1][4*(r&1)+3]=f2bf(v.w);
    }
    qn[tid] = sqrtf(ssq);
    #pragma unroll
    for (int r=0;r<4;r++) *(short8*)&Pq[tid*QP + 8*r] = s8[r];
  }
  __syncthreads();
  short8 qfrag[3];
  float m_ln[3][4];
  #pragma unroll
  for (int t=0;t<3;t++) {
    qfrag[t] = *(short8*)&Pq[(48*w + 16*t + l16)*QP + quad*8];
    #pragma unroll
    for (int r=0;r<4;r++) m_ln[t][r] = qn[48*w + 16*t + 4*quad + r];
  }
  f32x4 acc[3][4];
  #pragma unroll
  for (int mt=0;mt<3;mt++)
    #pragma unroll
    for (int nt=0;nt<4;nt++) acc[mt][nt] = (f32x4){0.f,0.f,0.f,0.f};
  float sspart[12];
  #pragma unroll
  for (int i=0;i<12;i++) sspart[i]=0.f;

  for (int tt = 0; tt < 3; tt++) {
    int kk = (tt == 0) ? kch : ((tt == 1) ? (kch + NCHUNK - 1) % NCHUNK : (kch + 1) % NCHUNK);
    for (int hh = 0; hh < 2; hh++) {
      int off = hh ? 96 : 0;
      int KC  = hh ? 48 : 96;       // keys this sub-tile
      int NT  = hh ? 3  : 6;        // S n-tiles (16 keys each)
      int KF  = hh ? 2  : 3;        // PV k-frags (32 keys each; hh=1 cols 48..63 zero-pad)
      __syncthreads();   // previous sub-tile fully consumed (and prologue Q-frag reads done)
      // stage K: one thread per key row, fp32 norm then bf16
      if (tid < KC) {
        int tok = sidx[base + kk*CHUNK + off + tid] % LTOK;
        const float4* kr = (const float4*)(xe + ((size_t)n*LTOK + tok)*CM);
        float ssq = 0.f; float vv[32];
        #pragma unroll
        for (int r=0;r<8;r++) {
          float4 v = kr[r];
          vv[4*r]=v.x; vv[4*r+1]=v.y; vv[4*r+2]=v.z; vv[4*r+3]=v.w;
          ssq = fmaf(v.x,v.x,ssq); ssq = fmaf(v.y,v.y,ssq);
          ssq = fmaf(v.z,v.z,ssq); ssq = fmaf(v.w,v.w,ssq);
        }
        float rn = 1.f / fmaxf(sqrtf(ssq), 5e-5f);
        #pragma unroll
        for (int r=0;r<4;r++) {
          short8 s8;
          #pragma unroll
          for (int j=0;j<8;j++) s8[j] = f2bf(vv[8*r+j]*rn);
          *(short8*)&Kb[tid*QP + 8*r] = s8;
        }
      }
      // stage V transposed: task = (chgroup g of 4, key); key contiguous across threads
      int ntask = KC*16, nit = ntask/192;
      for (int it=0; it<nit; it++) {
        int idx = tid + 192*it;
        int g = idx / KC, key = idx - g*KC;
        int tok = sidx[base + kk*CHUNK + off + key] % LTOK;
        float4 v = *(const float4*)(ye + ((size_t)n*LTOK + tok)*CO + 4*g);
        VbT[(4*g+0)*PP + key] = f2bf(v.x);
        VbT[(4*g+1)*PP + key] = f2bf(v.y);
        VbT[(4*g+2)*PP + key] = f2bf(v.z);
        VbT[(4*g+3)*PP + key] = f2bf(v.w);
      }
      __syncthreads();
      if (hh == 1 && lane < 48) {   // zero P cols 48..63 (pad for last k-frag); wave-private rows
        int row = 48*w + lane;
        *(short8*)&Pq[row*PP + 48] = (short8){0,0,0,0,0,0,0,0};
        *(short8*)&Pq[row*PP + 56] = (short8){0,0,0,0,0,0,0,0};
      }
      // ---- S = Q . K^T, exp, write P (bf16, A-frag layout), accumulate row sums ----
      for (int nt = 0; nt < NT; nt++) {
        short8 bfr = *(short8*)&Kb[(16*nt + l16)*QP + quad*8];
        f32x4 c[3];
        #pragma unroll
        for (int mt=0;mt<3;mt++)
          c[mt] = __builtin_amdgcn_mfma_f32_16x16x32_bf16(qfrag[mt], bfr, (f32x4){0.f,0.f,0.f,0.f}, 0, 0, 0);
        #pragma unroll
        for (int mt=0;mt<3;mt++) {
          #pragma unroll
          for (int reg=0;reg<4;reg++) {
            float p = __expf(c[mt][reg] - m_ln[mt][reg]);
            sspart[mt*4+reg] += p;
            int row = 48*w + 16*mt + 4*quad + reg;
            Pq[row*PP + 16*nt + l16] = f2bf(p);
          }
        }
      }
      // ---- PV: ret += P . V ----
      for (int kf = 0; kf < KF; kf++) {
        short8 afr[3];
        #pragma unroll
        for (int mt=0;mt<3;mt++)
          afr[mt] = *(short8*)&Pq[(48*w + 16*mt + l16)*PP + kf*32 + quad*8];
        #pragma unroll
        for (int nt2=0;nt2<4;nt2++) {
          short8 vfr = *(short8*)&VbT[(16*nt2 + l16)*PP + kf*32 + quad*8];
          #pragma unroll
          for (int mt=0;mt<3;mt++)
            acc[mt][nt2] = __builtin_amdgcn_mfma_f32_16x16x32_bf16(afr[mt], vfr, acc[mt][nt2], 0, 0, 0);
        }
      }
    }
  }
  // ---- epilogue: reduce row sums over the 16 cols (lanes l16), normalize, scatter ----
  #pragma unroll
  for (int i=0;i<12;i++) {
    float v = sspart[i];
    v += __shfl_xor(v, 1); v += __shfl_xor(v, 2);
    v += __shfl_xor(v, 4); v += __shfl_xor(v, 8);
    sspart[i] = v;
  }
  #pragma unroll
  for (int mt=0;mt<3;mt++) {
    #pragma unroll
    for (int reg=0;reg<4;reg++) {
      int row = 48*w + 16*mt + 4*quad + reg;
      int mtok = sidx[base + kch*CHUNK + row];     // full index h*L+t
      float ssum = sspart[mt*4+reg];
      float inv = 1.f / ssum;
      float* rp = ret + ((size_t)n*TOT + mtok)*CO;
      #pragma unroll
      for (int nt2=0;nt2<4;nt2++) rp[16*nt2 + l16] = acc[mt][nt2][reg] * inv;
      if (l16 == 0) bsc[(size_t)n*TOT + mtok] = m_ln[mt][reg] + logf(ssum);
    }
  }
}

// ---------------- combine 4 hash rounds (softmax over bscore) + residual, NCHW out ----------
__global__ void k_combine(const float* __restrict__ ret, const float* __restrict__ bsc,
                          const float* __restrict__ c2, float* __restrict__ out) {
  int blk = blockIdx.x;                 // NB * (LTOK/16)
  int n  = blk / (LTOK/16);
  int t0 = (blk % (LTOK/16)) * 16;
  __shared__ float rl[NH][16][CO+1];
  __shared__ float pw[NH][16];
  int tid = threadIdx.x;
  for (int h = 0; h < NH; h++)
    for (int e = tid; e < 16*CO; e += 256) {
      int tl = e >> 6, f = e & 63;
      rl[h][tl][f] = ret[((size_t)n*TOT + h*LTOK + t0 + tl)*CO + f];
    }
  if (tid < 16) {
    float b0[NH]; float mm = -INFINITY;
    #pragma unroll
    for (int h = 0; h < NH; h++) { b0[h] = bsc[(size_t)n*TOT + h*LTOK + t0 + tid]; mm = fmaxf(mm, b0[h]); }
    float s = 0.f;
    #pragma unroll
    for (int h = 0; h < NH; h++) { b0[h] = __expf(b0[h] - mm); s += b0[h]; }
    float inv = 1.f / s;
    #pragma unroll
    for (int h = 0; h < NH; h++) pw[h][tid] = b0[h] * inv;
  }
  __syncthreads();
  int tl = tid & 15;
  int cog = tid >> 4;     // 0..15
  #pragma unroll
  for (int cc = 0; cc < 4; cc++) {
    int co = cog + 16*cc;
    size_t oi = ((size_t)(n*CO + co))*LTOK + t0 + tl;
    float a = c2[oi];
    #pragma unroll
    for (int h = 0; h < NH; h++) a = fmaf(pw[h][tl], rl[h][tl][co], a);
    out[oi] = a;
  }
}

extern "C" void kernel_launch(void* const* d_in, const int* in_sizes, int n_in,
                              void* d_out, int out_size, void* d_ws, size_t ws_size,
                              hipStream_t stream) {
  const float* x   = (const float*)d_in[0];
  const float* w1  = (const float*)d_in[1];
  const float* b1  = (const float*)d_in[2];
  const float* w2  = (const float*)d_in[3];
  const float* b2  = (const float*)d_in[4];
  const float* wm  = (const float*)d_in[5];
  const float* bm  = (const float*)d_in[6];
  const float* wa  = (const float*)d_in[7];
  const float* ba  = (const float*)d_in[8];
  const float* rot = (const float*)d_in[9];
  float* out = (float*)d_out;

  float* ws  = (float*)d_ws;
  float* up  = ws;                    // 2359296
  float* c1  = up  + 2359296;         // 2359296
  float* c2  = c1  + 2359296;         // 2359296
  float* xep = c2  + 2359296;         // 1179648  [n][t][32]
  float* yep = xep + 1179648;         // 2359296  [n][t][64]
  float* bsc = yep + 2359296;         // 147456   [n][h*L+t]
  float* ret = bsc + 147456;          // 9437184  [n][h*L+t][64]
  int* codes  = (int*)(ret + 9437184);// 147456
  int* sidx   = codes + 147456;       // 147456
  int* hist   = sidx + 147456;        // 73728
  int* bstart = hist + 73728;         // 73728
  short* w1H = (short*)(bstart + 73728); // 36864 shorts each plane
  short* w1L = w1H + 36864;
  short* w2H = w1L + 36864;
  short* w2L = w2H + 36864;
  short* wmH = w2L + 36864;           // 18432
  short* wmL = wmH + 18432;
  (void)in_sizes; (void)n_in; (void)out_size; (void)ws_size;

  k_wprep<<<dim3((9*64*64 + 255)/256), dim3(256), 0, stream>>>(w1, w1H, w1L, 64);
  k_wprep<<<dim3((9*64*64 + 255)/256), dim3(256), 0, stream>>>(w2, w2H, w2L, 64);
  k_wprep<<<dim3((9*32*64 + 255)/256), dim3(256), 0, stream>>>(wm, wmH, wmL, 32);
  k_upsample<<<dim3((NB*CIN*HH*WW + 255)/256), dim3(256), 0, stream>>>(x, up);
  k_conv3m<64,false,true><<<dim3(NB*72), dim3(256), 0, stream>>>(up, w1H, w1L, b1, c1);
  k_conv3m<64,false,true><<<dim3(NB*72), dim3(256), 0, stream>>>(c1, w2H, w2L, b2, c2);
  k_conv3m<32,true,false><<<dim3(NB*72), dim3(256), 0, stream>>>(c2, wmH, wmL, bm, xep);
  k_conv1x1<<<dim3(NB*(LTOK/128)), dim3(256), 0, stream>>>(c2, wa, ba, yep);
  k_hash<<<dim3(NB*NSB), dim3(SB), 0, stream>>>(xep, rot, codes, hist);
  k_offsets<<<dim3(NB), dim3(256), 0, stream>>>(hist, bstart);
  k_scatter<<<dim3(NB*NSB), dim3(SB), 0, stream>>>(codes, bstart, sidx);
  k_attn<<<dim3(NB*NH*NCHUNK), dim3(192), 0, stream>>>(xep, yep, sidx, ret, bsc);
  k_combine<<<dim3(NB*(LTOK/16)), dim3(256), 0, stream>>>(ret, bsc, c2, out);
}

// Round 6
// 386.771 us; speedup vs baseline: 4.9662x; 1.0480x over previous
//
#include <hip/hip_runtime.h>
#include <math.h>

#define NB 4
#define CIN 64
#define CO 64
#define CM 32
#define H0 48
#define W0 48
#define HH 96
#define WW 96
#define LTOK (HH*WW)     // 9216 tokens per image
#define NH 4
#define NBUCK 64
#define CHUNK 144
#define NCHUNK 64        // LTOK / CHUNK
#define TOT (NH*LTOK)    // 36864
#define SB 512
#define NSB (TOT/SB)     // 72

typedef __attribute__((ext_vector_type(8))) short short8;
typedef __attribute__((ext_vector_type(4))) short short4v;
typedef __attribute__((ext_vector_type(4))) float f32x4;

__device__ __forceinline__ short f2bf(float f) {
  union { float f; unsigned u; } v; v.f = f;
  unsigned r = v.u + 0x7fffu + ((v.u >> 16) & 1u);
  return (short)(r >> 16);
}
__device__ __forceinline__ float bf2f(short h) {
  union { float f; unsigned u; } v; v.u = ((unsigned)(unsigned short)h) << 16;
  return v.f;
}
__device__ __forceinline__ short8 ld_b64x2(const short* p) {  // 8B-aligned pair load
  short4v a = *(const short4v*)p;
  short4v b = *(const short4v*)(p+4);
  short8 r; r[0]=a[0];r[1]=a[1];r[2]=a[2];r[3]=a[3];r[4]=b[0];r[5]=b[1];r[6]=b[2];r[7]=b[3];
  return r;
}

// ---------------- bicubic upsample (jax.image.resize, cubic a=-0.5, half-pixel) ----------------
__device__ __forceinline__ void cubic_taps(int o, int insz, int* p, float* w) {
  int j = o >> 1;
  const float B0=-0.0234375f, B1=0.2265625f, B2=0.8671875f, B3=-0.0703125f;
  if ((o & 1) == 0) { p[0]=j-2;p[1]=j-1;p[2]=j;  p[3]=j+1; w[0]=B0;w[1]=B1;w[2]=B2;w[3]=B3; }
  else              { p[0]=j-1;p[1]=j;  p[2]=j+1;p[3]=j+2; w[0]=B3;w[1]=B2;w[2]=B1;w[3]=B0; }
  float s = 0.f;
  #pragma unroll
  for (int a=0;a<4;a++){ if (p[a] < 0 || p[a] >= insz) p[a] = -1; else s += w[a]; }
  float inv = 1.f / s;
  #pragma unroll
  for (int a=0;a<4;a++) w[a] *= inv;
}

__global__ void k_upsample(const float* __restrict__ x, float* __restrict__ up) {
  int i = blockIdx.x*blockDim.x + threadIdx.x;
  if (i >= NB*CIN*HH*WW) return;
  int ox = i % WW; int t = i / WW;
  int oy = t % HH; t /= HH;
  int c = t % CIN; int n = t / CIN;
  int px[4]; float wx[4]; cubic_taps(ox, W0, px, wx);
  int py[4]; float wy[4]; cubic_taps(oy, H0, py, wy);
  const float* src = x + ((size_t)(n*CIN + c))*H0*W0;
  float acc = 0.f;
  #pragma unroll
  for (int a=0;a<4;a++) {
    if (py[a] < 0) continue;
    const float* r = src + py[a]*W0;
    float ra = 0.f;
    #pragma unroll
    for (int b=0;b<4;b++) if (px[b] >= 0) ra = fmaf(wx[b], r[px[b]], ra);
    acc = fmaf(wy[a], ra, acc);
  }
  up[i] = acc;
}

// ---------------- weight prep: fp32 [co][ci][3][3] -> bf16 hi/lo planes [s][co][ci] ----------
__global__ void k_wprep(const float* __restrict__ w, short* __restrict__ dH,
                        short* __restrict__ dL, int couts) {
  int i = blockIdx.x*blockDim.x + threadIdx.x;
  int n = 9*couts*64;
  if (i >= n) return;
  int ci = i & 63; int t = i >> 6; int co = t % couts; int s = t / couts;
  float v = w[((size_t)(co*64 + ci))*9 + s];
  short hi = f2bf(v);
  dH[i] = hi;
  dL[i] = f2bf(v - bf2f(hi));
}

// ---------------- token prep: xep fp32 -> bf16 Q rows, bf16 normalized K rows, norms --------
__global__ void k_prep(const float* __restrict__ xe, short* __restrict__ xqb,
                       short* __restrict__ xkb, float* __restrict__ qnb) {
  int i = blockIdx.x*blockDim.x + threadIdx.x;   // one thread per token, NB*LTOK
  if (i >= NB*LTOK) return;
  const float4* xr = (const float4*)(xe + (size_t)i*CM);
  float v[32]; float ssq = 0.f;
  #pragma unroll
  for (int r=0;r<8;r++) {
    float4 a = xr[r];
    v[4*r]=a.x; v[4*r+1]=a.y; v[4*r+2]=a.z; v[4*r+3]=a.w;
    ssq = fmaf(a.x,a.x,ssq); ssq = fmaf(a.y,a.y,ssq);
    ssq = fmaf(a.z,a.z,ssq); ssq = fmaf(a.w,a.w,ssq);
  }
  float nrm = sqrtf(ssq);
  float rn = 1.f / fmaxf(nrm, 5e-5f);
  qnb[i] = nrm;
  #pragma unroll
  for (int r=0;r<4;r++) {
    short8 q8, k8;
    #pragma unroll
    for (int j=0;j<8;j++) { q8[j] = f2bf(v[8*r+j]); k8[j] = f2bf(v[8*r+j]*rn); }
    *(short8*)&xqb[(size_t)i*CM + 8*r] = q8;
    *(short8*)&xkb[(size_t)i*CM + 8*r] = k8;
  }
}

// ---------------- 3x3 conv as implicit GEMM over 9 shifts, bf16 MFMA (W split hi/lo) --------
#define XP 36   // X LDS pitch in shorts
#define WP 40   // W LDS pitch in shorts
template<int COUTS, bool TMAJ, bool RELU>
__global__ __launch_bounds__(256) void k_conv3m(const float* __restrict__ in,
                          const short* __restrict__ wH, const short* __restrict__ wL,
                          const float* __restrict__ bias, float* __restrict__ out) {
  int blk = blockIdx.x;              // NB*72
  int n  = blk / 72;
  int t0 = (blk % 72) * 128;
  int tid = threadIdx.x;
  int wv = tid >> 6, lane = tid & 63, quad = lane >> 4, l16 = lane & 15;
  __shared__ __align__(16) short XB[128*XP];
  __shared__ __align__(16) short WHs[COUTS*WP];
  __shared__ __align__(16) short WLs[COUTS*WP];
  __shared__ float biasl[COUTS];
  if (tid < COUTS) biasl[tid] = bias[tid];
  const int MT = TMAJ ? 2 : 4;
  const int NWT = COUTS/16;
  f32x4 acc[4][2];
  #pragma unroll
  for (int a=0;a<4;a++)
    #pragma unroll
    for (int b=0;b<2;b++) acc[a][b] = (f32x4){0.f,0.f,0.f,0.f};

  const float* inb = in + (size_t)n*CIN*LTOK;
  for (int s = 0; s < 9; s++) {
    int dy = s/3 - 1, dx = s%3 - 1;
    for (int cih = 0; cih < 2; cih++) {
      __syncthreads();
      #pragma unroll
      for (int it = 0; it < 8; it++) {
        int idx = tid + 256*it;
        int tok = idx & 127, c = idx >> 7;
        int t = t0 + tok;
        int y = t / WW, x = t - y*WW;
        int ys = y + dy, xs = x + dx;
        float v0 = 0.f, v1 = 0.f;
        if ((unsigned)ys < HH && (unsigned)xs < WW) {
          const float* p = inb + ((size_t)(cih*32 + 2*c))*LTOK + ys*WW + xs;
          v0 = p[0]; v1 = p[LTOK];
        }
        unsigned pk = (unsigned)(unsigned short)f2bf(v0) | (((unsigned)(unsigned short)f2bf(v1)) << 16);
        ((unsigned*)XB)[tok*(XP/2) + c] = pk;
      }
      #pragma unroll
      for (int it = 0; it < (COUTS*32)/(2*256); it++) {
        int idx = tid + 256*it;
        int co = idx >> 4, cp = idx & 15;
        int gsrc = ((s*COUTS + co)*64 + cih*32) >> 1;
        ((unsigned*)WHs)[co*(WP/2) + cp] = ((const unsigned*)wH)[gsrc + cp];
        ((unsigned*)WLs)[co*(WP/2) + cp] = ((const unsigned*)wL)[gsrc + cp];
      }
      __syncthreads();
      if (!TMAJ) {
        short8 xf[2];
        #pragma unroll
        for (int nt=0;nt<2;nt++)
          xf[nt] = ld_b64x2(&XB[(wv*32 + nt*16 + l16)*XP + quad*8]);
        #pragma unroll
        for (int mt=0;mt<4;mt++) {
          short8 wh = *(const short8*)&WHs[(mt*16 + l16)*WP + quad*8];
          short8 wl = *(const short8*)&WLs[(mt*16 + l16)*WP + quad*8];
          #pragma unroll
          for (int nt=0;nt<2;nt++) {
            acc[mt][nt] = __builtin_amdgcn_mfma_f32_16x16x32_bf16(wh, xf[nt], acc[mt][nt], 0, 0, 0);
            acc[mt][nt] = __builtin_amdgcn_mfma_f32_16x16x32_bf16(wl, xf[nt], acc[mt][nt], 0, 0, 0);
          }
        }
      } else {
        short8 xf[2];
        #pragma unroll
        for (int mt=0;mt<MT;mt++)
          xf[mt] = ld_b64x2(&XB[(wv*32 + mt*16 + l16)*XP + quad*8]);
        #pragma unroll
        for (int nt=0;nt<NWT;nt++) {
          short8 wh = *(const short8*)&WHs[(nt*16 + l16)*WP + quad*8];
          short8 wl = *(const short8*)&WLs[(nt*16 + l16)*WP + quad*8];
          #pragma unroll
          for (int mt=0;mt<MT;mt++) {
            acc[mt][nt] = __builtin_amdgcn_mfma_f32_16x16x32_bf16(xf[mt], wh, acc[mt][nt], 0, 0, 0);
            acc[mt][nt] = __builtin_amdgcn_mfma_f32_16x16x32_bf16(xf[mt], wl, acc[mt][nt], 0, 0, 0);
          }
        }
      }
    }
  }
  if (!TMAJ) {
    #pragma unroll
    for (int mt=0;mt<4;mt++) {
      #pragma unroll
      for (int nt=0;nt<2;nt++) {
        int tokl = wv*32 + nt*16 + l16;
        #pragma unroll
        for (int reg=0;reg<4;reg++) {
          int co = mt*16 + quad*4 + reg;
          float v = acc[mt][nt][reg] + biasl[co];
          if (RELU) v = fmaxf(v, 0.f);
          out[((size_t)(n*COUTS + co))*LTOK + t0 + tokl] = v;
        }
      }
    }
  } else {
    #pragma unroll
    for (int mt=0;mt<MT;mt++) {
      #pragma unroll
      for (int nt=0;nt<NWT;nt++) {
        int co = nt*16 + l16;
        #pragma unroll
        for (int reg=0;reg<4;reg++) {
          int t = t0 + wv*32 + mt*16 + quad*4 + reg;
          float v = acc[mt][nt][reg] + biasl[co];
          if (RELU) v = fmaxf(v, 0.f);
          out[((size_t)n*LTOK + t)*COUTS + co] = v;
        }
      }
    }
  }
}

// ---------------- 1x1 conv as LDS-tiled GEMM -> bf16 token-major V [n][t][64] ----------------
__global__ __launch_bounds__(256) void k_conv1x1(const float* __restrict__ in, const float* __restrict__ w,
                          const float* __restrict__ bias, short* __restrict__ out) {
  int blk = blockIdx.x;           // NB * 72
  int n  = blk / (LTOK/128);
  int t0 = (blk % (LTOK/128)) * 128;
  int tid = threadIdx.x;
  __shared__ float Wl[64*64];     // [ci][co]
  __shared__ float Xl[64][128];
  for (int e=tid; e<4096; e+=256) {
    int ci=e>>6, co=e&63;
    Wl[e] = w[co*CIN + ci];
  }
  for (int e=tid; e<64*128; e+=256) {
    int ci=e>>7, t=e&127;
    Xl[ci][t] = in[(size_t)n*CIN*LTOK + (size_t)ci*LTOK + t0 + t];
  }
  __syncthreads();
  int co = tid & 63, tg = tid >> 6;
  float acc[32];
  float bv = bias[co];
  #pragma unroll
  for (int i=0;i<32;i++) acc[i]=bv;
  for (int ci=0;ci<64;ci++){
    float wv = Wl[ci*64+co];
    const float4* xr = (const float4*)&Xl[ci][tg*32];
    #pragma unroll
    for (int r=0;r<8;r++){
      float4 xv = xr[r];
      acc[4*r+0]=fmaf(wv,xv.x,acc[4*r+0]);
      acc[4*r+1]=fmaf(wv,xv.y,acc[4*r+1]);
      acc[4*r+2]=fmaf(wv,xv.z,acc[4*r+2]);
      acc[4*r+3]=fmaf(wv,xv.w,acc[4*r+3]);
    }
  }
  short* ob = out + ((size_t)n*LTOK + t0 + tg*32)*CO + co;
  #pragma unroll
  for (int i=0;i<32;i++) ob[(size_t)i*CO] = f2bf(acc[i]);
}

// ---------------- LSH hash: codes + per-block histogram ----------------
__global__ void k_hash(const float* __restrict__ xe, const float* __restrict__ rot,
                       int* __restrict__ codes, int* __restrict__ hist) {
  int b  = blockIdx.x;
  int n  = b / NSB;
  int bb = b % NSB;
  int j  = bb*SB + threadIdx.x;
  int h  = j / LTOK;
  int t  = j % LTOK;
  __shared__ float rl[CM][NBUCK/2];
  __shared__ int lh[256];
  for (int e = threadIdx.x; e < 256; e += SB) lh[e] = 0;
  for (int e = threadIdx.x; e < CM*(NBUCK/2); e += SB) {
    int f = e / 32, i = e % 32;
    rl[f][i] = rot[(f*NH + h)*32 + i];
  }
  __syncthreads();
  float q[CM];
  const float4* xr4 = (const float4*)(xe + ((size_t)n*LTOK + t)*CM);
  #pragma unroll
  for (int r = 0; r < 8; r++) {
    float4 v = xr4[r];
    q[4*r+0]=v.x; q[4*r+1]=v.y; q[4*r+2]=v.z; q[4*r+3]=v.w;
  }
  float bp = -INFINITY, bn = -INFINITY; int ip = 0, inn = 0;
  for (int i = 0; i < 32; i++) {
    float acc = 0.f;
    #pragma unroll
    for (int f = 0; f < CM; f++) acc = fmaf(q[f], rl[f][i], acc);
    if (acc  > bp) { bp = acc;  ip  = i; }
    if (-acc > bn) { bn = -acc; inn = i; }
  }
  int code = (bp >= bn) ? ip : (32 + inn);
  code += h * NBUCK;
  codes[n*TOT + j] = code;
  atomicAdd(&lh[code], 1);
  __syncthreads();
  for (int e = threadIdx.x; e < 256; e += SB) hist[((size_t)(n*NSB + bb))*256 + e] = lh[e];
}

// ---------------- stable counting sort ----------------
__global__ void k_offsets(const int* __restrict__ hist, int* __restrict__ bstart) {
  int n = blockIdx.x; int c = threadIdx.x;
  int tot = 0;
  for (int b = 0; b < NSB; b++) tot += hist[((size_t)(n*NSB + b))*256 + c];
  __shared__ int sc[256];
  sc[c] = tot;
  __syncthreads();
  for (int d = 1; d < 256; d <<= 1) {
    int u = (c >= d) ? sc[c-d] : 0;
    __syncthreads();
    sc[c] += u;
    __syncthreads();
  }
  int run = sc[c] - tot;
  for (int b = 0; b < NSB; b++) {
    bstart[((size_t)(n*NSB + b))*256 + c] = run;
    run += hist[((size_t)(n*NSB + b))*256 + c];
  }
}

__global__ void k_scatter(const int* __restrict__ codes, const int* __restrict__ bstart,
                          int* __restrict__ sidx) {
  int b = blockIdx.x; int n = b / NSB; int bb = b % NSB;
  int j = bb*SB + threadIdx.x;
  int code = codes[n*TOT + j];
  __shared__ unsigned char lc[SB];
  lc[threadIdx.x] = (unsigned char)code;
  __syncthreads();
  int rank = 0;
  unsigned char my = (unsigned char)code;
  for (int e = 0; e < threadIdx.x; e++) rank += (lc[e] == my) ? 1 : 0;
  int pos = bstart[((size_t)(n*NSB + bb))*256 + code] + rank;
  sidx[n*TOT + pos] = j;
}

// ---------------- MFMA bf16 flash attention: 2 chunks/block, K/Q frags from global ----------
// block = 192 thr (3 waves); wave w owns query rows 48w..48w+47. m = ||q|| exact.
#define PQP 168   // P / V^T pitch in shorts (160 key cols + 8 pad; 16B aligned)
__global__ __launch_bounds__(192,1) void k_attn(const short* __restrict__ xqb,
                       const short* __restrict__ xkb, const float* __restrict__ qnb,
                       const short* __restrict__ yvb, const int* __restrict__ sidx,
                       float* __restrict__ ret, float* __restrict__ bsc) {
  int blk = blockIdx.x;               // 512 = NB*NH*NCHUNK/2
  int cpair = blk % (NCHUNK/2);
  int h = (blk / (NCHUNK/2)) % NH;
  int n = blk / ((NCHUNK/2)*NH);
  const int base = n*TOT + h*LTOK;
  __shared__ __align__(16) short Pq[144*PQP];   // P (bf16), cols 144..159 zero pad
  __shared__ __align__(16) short VbT[64*PQP];   // V^T bf16 [ch][key], cols 144..159 zero pad
  __shared__ int sj[3*CHUNK];
  int tid = threadIdx.x;
  int w = tid >> 6, lane = tid & 63, quad = lane >> 4, l16 = lane & 15;
  const short* xq = xqb + (size_t)n*LTOK*CM;
  const short* xk = xkb + (size_t)n*LTOK*CM;
  const short* yv = yvb + (size_t)n*LTOK*CO;
  const float* qn = qnb + (size_t)n*LTOK;

  // one-time zero of the PV over-read pad (cols 144..159). LDS is otherwise virgin/garbage,
  // and bf16 garbage can encode NaN/Inf: 0 (P pad) * NaN (V pad) = NaN. Both pads must be 0.
  // Staging and S-phase never write these columns, so zero once per block.
  for (int e = tid; e < 144*8; e += 192) {   // Pq pad: 1152 dwords
    int r = e >> 3, d = e & 7;
    ((unsigned*)Pq)[r*(PQP/2) + 72 + d] = 0u;
  }
  for (int e = tid; e < 64*8; e += 192) {    // VbT pad: 512 dwords
    int r = e >> 3, d = e & 7;
    ((unsigned*)VbT)[r*(PQP/2) + 72 + d] = 0u;
  }

  for (int ch2 = 0; ch2 < 2; ch2++) {
    int kch = cpair*2 + ch2;
    int kprev = (kch + NCHUNK - 1) % NCHUNK, knext = (kch + 1) % NCHUNK;
    __syncthreads();   // previous chunk fully done (sj/Pq/VbT reusable); pad zeroing visible
    for (int e = tid; e < 3*CHUNK; e += 192) {
      int tt = e / CHUNK, r = e - tt*CHUNK;
      int kk = (tt==0) ? kch : ((tt==1) ? kprev : knext);
      sj[e] = sidx[base + kk*CHUNK + r];
    }
    __syncthreads();
    // Q frags + per-row max (= ||q||) straight from global
    short8 qfrag[3]; float m_ln[3][4];
    #pragma unroll
    for (int mt=0;mt<3;mt++) {
      int tok = sj[48*w + 16*mt + l16] % LTOK;
      qfrag[mt] = *(const short8*)(xq + (size_t)tok*CM + quad*8);
      #pragma unroll
      for (int r=0;r<4;r++)
        m_ln[mt][r] = qn[sj[48*w + 16*mt + 4*quad + r] % LTOK];
    }
    f32x4 acc[3][4];
    #pragma unroll
    for (int mt=0;mt<3;mt++)
      #pragma unroll
      for (int nt=0;nt<4;nt++) acc[mt][nt] = (f32x4){0.f,0.f,0.f,0.f};
    float sspart[12];
    #pragma unroll
    for (int i=0;i<12;i++) sspart[i]=0.f;

    for (int tt = 0; tt < 3; tt++) {
      __syncthreads();   // previous tile's VbT fully consumed
      // ---- stage V^T (bf16 copy-transpose): 8 ch-groups x 144 keys ----
      #pragma unroll
      for (int it = 0; it < 6; it++) {
        int idx = tid + 192*it;
        int g = idx / CHUNK, key = idx - g*CHUNK;
        int tok = sj[tt*CHUNK + key] % LTOK;
        short8 v = *(const short8*)(yv + (size_t)tok*CO + 8*g);
        #pragma unroll
        for (int i=0;i<8;i++) VbT[(8*g+i)*PQP + key] = v[i];
      }
      __syncthreads();
      // ---- S = Q.K^T (B-frags from global), exp, write P ----
      int ktok[9];
      #pragma unroll
      for (int nt=0;nt<9;nt++) ktok[nt] = sj[tt*CHUNK + 16*nt + l16] % LTOK;
      #pragma unroll
      for (int nt = 0; nt < 9; nt++) {
        short8 bfr = *(const short8*)(xk + (size_t)ktok[nt]*CM + quad*8);
        f32x4 c[3];
        #pragma unroll
        for (int mt=0;mt<3;mt++)
          c[mt] = __builtin_amdgcn_mfma_f32_16x16x32_bf16(qfrag[mt], bfr, (f32x4){0.f,0.f,0.f,0.f}, 0, 0, 0);
        #pragma unroll
        for (int mt=0;mt<3;mt++) {
          #pragma unroll
          for (int reg=0;reg<4;reg++) {
            float p = __expf(c[mt][reg] - m_ln[mt][reg]);
            sspart[mt*4+reg] += p;
            Pq[(48*w + 16*mt + 4*quad + reg)*PQP + 16*nt + l16] = f2bf(p);
          }
        }
      }
      // ---- PV: 5 k-frags of 32 (cols 144..159 are zero in BOTH P and V^T) ----
      #pragma unroll
      for (int kf = 0; kf < 5; kf++) {
        short8 afr[3];
        #pragma unroll
        for (int mt=0;mt<3;mt++)
          afr[mt] = *(const short8*)&Pq[(48*w + 16*mt + l16)*PQP + kf*32 + quad*8];
        #pragma unroll
        for (int nt2=0;nt2<4;nt2++) {
          short8 vfr = *(const short8*)&VbT[(16*nt2 + l16)*PQP + kf*32 + quad*8];
          #pragma unroll
          for (int mt=0;mt<3;mt++)
            acc[mt][nt2] = __builtin_amdgcn_mfma_f32_16x16x32_bf16(afr[mt], vfr, acc[mt][nt2], 0, 0, 0);
        }
      }
    }
    // ---- epilogue ----
    #pragma unroll
    for (int i=0;i<12;i++) {
      float v = sspart[i];
      v += __shfl_xor(v, 1); v += __shfl_xor(v, 2);
      v += __shfl_xor(v, 4); v += __shfl_xor(v, 8);
      sspart[i] = v;
    }
    #pragma unroll
    for (int mt=0;mt<3;mt++) {
      #pragma unroll
      for (int reg=0;reg<4;reg++) {
        int row = 48*w + 16*mt + 4*quad + reg;
        int mtok = sj[row];                      // full id h*L+t
        float ssum = sspart[mt*4+reg];
        float inv = 1.f / ssum;
        float* rp = ret + ((size_t)n*TOT + mtok)*CO;
        #pragma unroll
        for (int nt2=0;nt2<4;nt2++) rp[16*nt2 + l16] = acc[mt][nt2][reg] * inv;
        if (l16 == 0) bsc[(size_t)n*TOT + mtok] = m_ln[mt][reg] + logf(ssum);
      }
    }
  }
}

// ---------------- combine 4 hash rounds (softmax over bscore) + residual, NCHW out ----------
__global__ void k_combine(const float* __restrict__ ret, const float* __restrict__ bsc,
                          const float* __restrict__ c2, float* __restrict__ out) {
  int blk = blockIdx.x;                 // NB * (LTOK/16)
  int n  = blk / (LTOK/16);
  int t0 = (blk % (LTOK/16)) * 16;
  __shared__ float rl[NH][16][CO+1];
  __shared__ float pw[NH][16];
  int tid = threadIdx.x;
  for (int h = 0; h < NH; h++)
    for (int e = tid; e < 16*CO; e += 256) {
      int tl = e >> 6, f = e & 63;
      rl[h][tl][f] = ret[((size_t)n*TOT + h*LTOK + t0 + tl)*CO + f];
    }
  if (tid < 16) {
    float b0[NH]; float mm = -INFINITY;
    #pragma unroll
    for (int h = 0; h < NH; h++) { b0[h] = bsc[(size_t)n*TOT + h*LTOK + t0 + tid]; mm = fmaxf(mm, b0[h]); }
    float s = 0.f;
    #pragma unroll
    for (int h = 0; h < NH; h++) { b0[h] = __expf(b0[h] - mm); s += b0[h]; }
    float inv = 1.f / s;
    #pragma unroll
    for (int h = 0; h < NH; h++) pw[h][tid] = b0[h] * inv;
  }
  __syncthreads();
  int tl = tid & 15;
  int cog = tid >> 4;
  #pragma unroll
  for (int cc = 0; cc < 4; cc++) {
    int co = cog + 16*cc;
    size_t oi = ((size_t)(n*CO + co))*LTOK + t0 + tl;
    float a = c2[oi];
    #pragma unroll
    for (int h = 0; h < NH; h++) a = fmaf(pw[h][tl], rl[h][tl][co], a);
    out[oi] = a;
  }
}

extern "C" void kernel_launch(void* const* d_in, const int* in_sizes, int n_in,
                              void* d_out, int out_size, void* d_ws, size_t ws_size,
                              hipStream_t stream) {
  const float* x   = (const float*)d_in[0];
  const float* w1  = (const float*)d_in[1];
  const float* b1  = (const float*)d_in[2];
  const float* w2  = (const float*)d_in[3];
  const float* b2  = (const float*)d_in[4];
  const float* wm  = (const float*)d_in[5];
  const float* bm  = (const float*)d_in[6];
  const float* wa  = (const float*)d_in[7];
  const float* ba  = (const float*)d_in[8];
  const float* rot = (const float*)d_in[9];
  float* out = (float*)d_out;

  float* ws  = (float*)d_ws;
  float* up  = ws;                    // 2359296 (dead after conv1 -> reused for xqb/xkb/qnb)
  float* c1  = up  + 2359296;         // 2359296 (dead after conv2 -> reused for yvb)
  float* c2  = c1  + 2359296;         // 2359296
  float* xep = c2  + 2359296;         // 1179648  [n][t][32] fp32 (hash + prep source)
  float* bsc = xep + 1179648;         // 147456
  float* ret = bsc + 147456;          // 9437184
  int* codes  = (int*)(ret + 9437184);// 147456
  int* sidx   = codes + 147456;       // 147456
  int* hist   = sidx + 147456;        // 73728
  int* bstart = hist + 73728;         // 73728
  short* w1H = (short*)(bstart + 73728);
  short* w1L = w1H + 36864;
  short* w2H = w1L + 36864;
  short* w2L = w2H + 36864;
  short* wmH = w2L + 36864;
  short* wmL = wmH + 18432;
  // overlays (write-after-read ordering enforced by launch order)
  short* xqb = (short*)up;            // 1179648 shorts
  short* xkb = xqb + 1179648;         // 1179648 shorts
  float* qnb = (float*)(xkb + 1179648); // 36864 floats  (total 4.86MB < up's 9.4MB)
  short* yvb = (short*)c1;            // 2359296 shorts (4.7MB < c1's 9.4MB)
  (void)in_sizes; (void)n_in; (void)out_size; (void)ws_size;

  k_wprep<<<dim3((9*64*64 + 255)/256), dim3(256), 0, stream>>>(w1, w1H, w1L, 64);
  k_wprep<<<dim3((9*64*64 + 255)/256), dim3(256), 0, stream>>>(w2, w2H, w2L, 64);
  k_wprep<<<dim3((9*32*64 + 255)/256), dim3(256), 0, stream>>>(wm, wmH, wmL, 32);
  k_upsample<<<dim3((NB*CIN*HH*WW + 255)/256), dim3(256), 0, stream>>>(x, up);
  k_conv3m<64,false,true><<<dim3(NB*72), dim3(256), 0, stream>>>(up, w1H, w1L, b1, c1);
  k_conv3m<64,false,true><<<dim3(NB*72), dim3(256), 0, stream>>>(c1, w2H, w2L, b2, c2);
  k_conv3m<32,true,false><<<dim3(NB*72), dim3(256), 0, stream>>>(c2, wmH, wmL, bm, xep);
  k_conv1x1<<<dim3(NB*(LTOK/128)), dim3(256), 0, stream>>>(c2, wa, ba, yvb);
  k_prep<<<dim3((NB*LTOK + 255)/256), dim3(256), 0, stream>>>(xep, xqb, xkb, qnb);
  k_hash<<<dim3(NB*NSB), dim3(SB), 0, stream>>>(xep, rot, codes, hist);
  k_offsets<<<dim3(NB), dim3(256), 0, stream>>>(hist, bstart);
  k_scatter<<<dim3(NB*NSB), dim3(SB), 0, stream>>>(codes, bstart, sidx);
  k_attn<<<dim3(NB*NH*NCHUNK/2), dim3(192), 0, stream>>>(xqb, xkb, qnb, yvb, sidx, ret, bsc);
  k_combine<<<dim3(NB*(LTOK/16)), dim3(256), 0, stream>>>(ret, bsc, c2, out);
}